// Round 1
// baseline (1233.952 us; speedup 1.0000x reference)
//
#include <hip/hip_runtime.h>
#include <math.h>

// SelfAttentionHybrid:
//   Q = X @ R            (8192x1024 @ 1024x1024)
//   K = X @ E            (8192x1024 @ 1024x1024)
//   S = softmax(Q K^T / 32)   per batch (4 x 2048x2048)
//   O = sigmoid(S @ X)        per batch
//
// fp32 everywhere (logits have std ~1024 -> softmax is near-argmax; low
// precision flips blend weights on near-tie rows). VALU SGEMM baseline.

#define TILE 128
#define BK 16

// C = alpha * A @ B(^T)  [+ sigmoid]
// A: (M x K) row-major, row stride K.
// B: NN: (K x N) row-major, row stride N.   NT: (N x K) row-major, row stride K.
// C: (M x N) row-major, row stride N.
// Batched via blockIdx.z with element strides sA, sB, sC.
template<bool BTRANS, bool SIGMOID>
__global__ __launch_bounds__(256)
void sgemm_kernel(const float* __restrict__ A, const float* __restrict__ B,
                  float* __restrict__ C, int N, int K,
                  long sA, long sB, long sC, float alpha)
{
    A += (long)blockIdx.z * sA;
    B += (long)blockIdx.z * sB;
    C += (long)blockIdx.z * sC;

    __shared__ float As[BK][TILE];   // As[k][m]
    __shared__ float Bs[BK][TILE];   // Bs[k][n]

    const int tid = threadIdx.x;
    const int tx = tid & 15;         // 16 thread cols
    const int ty = tid >> 4;         // 16 thread rows
    const int row0 = blockIdx.y * TILE;
    const int col0 = blockIdx.x * TILE;

    // A staging (and NT-B staging): 128x16 tile, 2 float4 per thread
    const int arow = tid >> 2;             // 0..63 (+64 second)
    const int acol = (tid & 3) << 2;       // 0,4,8,12
    // NN-B staging: 16x128 tile, 2 float4 per thread
    const int brow = tid >> 5;             // 0..7 (+8 second)
    const int bcol = (tid & 31) << 2;      // 0..124

    float acc[8][8];
    #pragma unroll
    for (int i = 0; i < 8; i++)
        #pragma unroll
        for (int j = 0; j < 8; j++)
            acc[i][j] = 0.0f;

    for (int k0 = 0; k0 < K; k0 += BK) {
        // ---- stage A (transpose into As[k][m]) ----
        #pragma unroll
        for (int i = 0; i < 2; i++) {
            const int r = arow + i * 64;
            const float4 v = *reinterpret_cast<const float4*>(
                A + (long)(row0 + r) * K + (k0 + acol));
            As[acol + 0][r] = v.x;
            As[acol + 1][r] = v.y;
            As[acol + 2][r] = v.z;
            As[acol + 3][r] = v.w;
        }
        // ---- stage B ----
        if (BTRANS) {
            #pragma unroll
            for (int i = 0; i < 2; i++) {
                const int r = arow + i * 64;    // n index within tile
                const float4 v = *reinterpret_cast<const float4*>(
                    B + (long)(col0 + r) * K + (k0 + acol));
                Bs[acol + 0][r] = v.x;
                Bs[acol + 1][r] = v.y;
                Bs[acol + 2][r] = v.z;
                Bs[acol + 3][r] = v.w;
            }
        } else {
            #pragma unroll
            for (int i = 0; i < 2; i++) {
                const int r = brow + i * 8;     // k index within tile
                *reinterpret_cast<float4*>(&Bs[r][bcol]) =
                    *reinterpret_cast<const float4*>(
                        B + (long)(k0 + r) * N + (col0 + bcol));
            }
        }
        __syncthreads();

        // ---- 8x8 micro-tile FMA, rows ty*4+{0..3,64..67}, cols tx*4+{0..3,64..67}
        #pragma unroll
        for (int kk = 0; kk < BK; kk++) {
            const float4 a0 = *reinterpret_cast<const float4*>(&As[kk][ty * 4]);
            const float4 a1 = *reinterpret_cast<const float4*>(&As[kk][ty * 4 + 64]);
            const float4 b0 = *reinterpret_cast<const float4*>(&Bs[kk][tx * 4]);
            const float4 b1 = *reinterpret_cast<const float4*>(&Bs[kk][tx * 4 + 64]);
            const float av[8] = {a0.x, a0.y, a0.z, a0.w, a1.x, a1.y, a1.z, a1.w};
            const float bv[8] = {b0.x, b0.y, b0.z, b0.w, b1.x, b1.y, b1.z, b1.w};
            #pragma unroll
            for (int i = 0; i < 8; i++)
                #pragma unroll
                for (int j = 0; j < 8; j++)
                    acc[i][j] = fmaf(av[i], bv[j], acc[i][j]);
        }
        __syncthreads();
    }

    // ---- epilogue ----
    #pragma unroll
    for (int i = 0; i < 8; i++) {
        const int rr = ty * 4 + ((i < 4) ? i : (64 + (i - 4)));
        #pragma unroll
        for (int jh = 0; jh < 2; jh++) {
            const int cc = tx * 4 + jh * 64;
            float4 v;
            v.x = alpha * acc[i][jh * 4 + 0];
            v.y = alpha * acc[i][jh * 4 + 1];
            v.z = alpha * acc[i][jh * 4 + 2];
            v.w = alpha * acc[i][jh * 4 + 3];
            if (SIGMOID) {
                v.x = 1.0f / (1.0f + __expf(-v.x));
                v.y = 1.0f / (1.0f + __expf(-v.y));
                v.z = 1.0f / (1.0f + __expf(-v.z));
                v.w = 1.0f / (1.0f + __expf(-v.w));
            }
            *reinterpret_cast<float4*>(C + (long)(row0 + rr) * N + (col0 + cc)) = v;
        }
    }
}

// In-place row softmax over 2048 columns; one block (256 thr) per row.
// Whole row lives in registers (8 floats/thread).
__global__ __launch_bounds__(256)
void softmax_kernel(float* __restrict__ S)
{
    const int NC = 2048;
    float* p = S + (long)blockIdx.x * NC;
    const int tid = threadIdx.x;

    float4 v0 = reinterpret_cast<float4*>(p)[tid];
    float4 v1 = reinterpret_cast<float4*>(p)[tid + 256];

    float m = fmaxf(fmaxf(fmaxf(v0.x, v0.y), fmaxf(v0.z, v0.w)),
                    fmaxf(fmaxf(v1.x, v1.y), fmaxf(v1.z, v1.w)));
    #pragma unroll
    for (int off = 1; off < 64; off <<= 1)
        m = fmaxf(m, __shfl_xor(m, off));

    __shared__ float redm[4];
    __shared__ float reds[4];
    const int wave = tid >> 6, lane = tid & 63;
    if (lane == 0) redm[wave] = m;
    __syncthreads();
    m = fmaxf(fmaxf(redm[0], redm[1]), fmaxf(redm[2], redm[3]));

    v0.x = __expf(v0.x - m); v0.y = __expf(v0.y - m);
    v0.z = __expf(v0.z - m); v0.w = __expf(v0.w - m);
    v1.x = __expf(v1.x - m); v1.y = __expf(v1.y - m);
    v1.z = __expf(v1.z - m); v1.w = __expf(v1.w - m);

    float s = (v0.x + v0.y + v0.z + v0.w) + (v1.x + v1.y + v1.z + v1.w);
    #pragma unroll
    for (int off = 1; off < 64; off <<= 1)
        s += __shfl_xor(s, off);
    if (lane == 0) reds[wave] = s;
    __syncthreads();
    s = (reds[0] + reds[1]) + (reds[2] + reds[3]);

    const float inv = 1.0f / s;
    v0.x *= inv; v0.y *= inv; v0.z *= inv; v0.w *= inv;
    v1.x *= inv; v1.y *= inv; v1.z *= inv; v1.w *= inv;

    reinterpret_cast<float4*>(p)[tid] = v0;
    reinterpret_cast<float4*>(p)[tid + 256] = v1;
}

extern "C" void kernel_launch(void* const* d_in, const int* in_sizes, int n_in,
                              void* d_out, int out_size, void* d_ws, size_t ws_size,
                              hipStream_t stream)
{
    const float* X   = (const float*)d_in[0];   // (4,2048,1024)
    const float* Rot = (const float*)d_in[1];   // (1024,1024)
    const float* Ent = (const float*)d_in[2];   // (1024,1024)
    float* out = (float*)d_out;

    const int B = 4, SQ = 2048, D = 1024;
    const long ND = (long)B * SQ * D;           // 8388608

    float* Q  = (float*)d_ws;                   // 32 MiB
    float* Km = Q + ND;                         // 32 MiB
    float* Sc = Km + ND;                        // 64 MiB (4 x 2048 x 2048)

    dim3 thr(256);

    // Q = X @ R ; K = X @ E   (flat 8192x1024 @ 1024x1024)
    sgemm_kernel<false, false><<<dim3(D / TILE, (B * SQ) / TILE, 1), thr, 0, stream>>>(
        X, Rot, Q, D, D, 0, 0, 0, 1.0f);
    sgemm_kernel<false, false><<<dim3(D / TILE, (B * SQ) / TILE, 1), thr, 0, stream>>>(
        X, Ent, Km, D, D, 0, 0, 0, 1.0f);

    // S = Q @ K^T / sqrt(D)   per batch
    sgemm_kernel<true, false><<<dim3(SQ / TILE, SQ / TILE, B), thr, 0, stream>>>(
        Q, Km, Sc, SQ, D, (long)SQ * D, (long)SQ * D, (long)SQ * SQ, 0.03125f);

    // softmax rows (4*2048 rows of 2048)
    softmax_kernel<<<dim3(B * SQ), thr, 0, stream>>>(Sc);

    // O = sigmoid(S @ X)      per batch
    sgemm_kernel<false, true><<<dim3(D / TILE, SQ / TILE, B), thr, 0, stream>>>(
        Sc, X, out, D, SQ, (long)SQ * SQ, (long)SQ * D, (long)SQ * D, 1.0f);
}

// Round 2
// 397.204 us; speedup vs baseline: 3.1066x; 3.1066x over previous
//
#include <hip/hip_runtime.h>
#include <hip/hip_bf16.h>
#include <math.h>

// SelfAttentionHybrid via split-bf16 (hi+lo) triple-MFMA fp32 emulation.
//   Q = X @ R ; K = X @ E            (8192x1024x1024 each)
//   S = softmax(Q K^T / 32)          (4 x 2048x2048, K=1024)
//   O = sigmoid(S @ X)               (4 x 2048x1024, K=2048)
// All GEMMs run as C = A(MxK) . B^T with B stored (N x K), both operands as
// (hi,lo) bf16 pairs; acc += Ahi*Bhi + Ahi*Blo + Alo*Bhi  (lo*lo ~2^-18 dropped).

using u16 = unsigned short;
using short8 = __attribute__((ext_vector_type(8))) short;
using f32x4  = __attribute__((ext_vector_type(4))) float;

__device__ static inline u16 f2bf(float f) {
    union { __hip_bfloat16 h; u16 u; } cv; cv.h = __float2bfloat16(f); return cv.u;
}
__device__ static inline float bf2f(u16 u) {
    union { __hip_bfloat16 h; u16 u; } cv; cv.u = u; return __bfloat162float(cv.h);
}
__device__ static inline void split2(float v, u16& h, u16& l) {
    h = f2bf(v);
    l = f2bf(v - bf2f(h));
}

__device__ static inline void gload16(const u16* g, u16* l) {
    __builtin_amdgcn_global_load_lds(
        (const __attribute__((address_space(1))) void*)g,
        (__attribute__((address_space(3))) void*)l, 16, 0, 0);
}

// LDS tile layout: [128 rows][32 bf16], row = 64B. 16B chunk index is
// XOR-swizzled: chunk_stored(c) holds k-group g = c ^ ((row>>1)&3).
// Readers (lanes 0..15 = consecutive rows at fixed k-group) then spread
// across all 32 banks at worst 2-way (free).
__device__ static inline short8 ldfrag(const u16* sm, int row, int g) {
    const int off = row * 32 + ((g ^ ((row >> 1) & 3)) << 3);
    return *reinterpret_cast<const short8*>(sm + off);
}

enum { EP_F32 = 0, EP_HILO = 1, EP_SIG = 2 };

template<int EPI>
__global__ __launch_bounds__(256)
void gemm_split(const u16* __restrict__ Ahi, const u16* __restrict__ Alo,
                const u16* __restrict__ Bhi, const u16* __restrict__ Blo,
                float* __restrict__ Cf, u16* __restrict__ Chi, u16* __restrict__ Clo,
                int K, int lda, int ldb, int ldc,
                long sA, long sB, long sC, float alpha)
{
    const int z = blockIdx.z;
    Ahi += z * sA; Alo += z * sA;
    Bhi += z * sB; Blo += z * sB;
    if (EPI == EP_HILO) { Chi += z * sC; Clo += z * sC; }
    else                { Cf  += z * sC; }

    __shared__ __align__(16) u16 smem[4 * 4096];  // Ahi | Alo | Bhi | Blo tiles
    u16* lAh = &smem[0];
    u16* lAl = &smem[4096];
    u16* lBh = &smem[8192];
    u16* lBl = &smem[12288];

    const int t = threadIdx.x;
    const int wave = t >> 6, lane = t & 63;
    const int row0 = blockIdx.y * 128, col0 = blockIdx.x * 128;

    // staging: thread t owns LDS slot (row = h*64 + t/4, chunk = t&3);
    // fetch the global k-group that the swizzle stores there.
    const int rr = t >> 2, cc = t & 3;
    const int gg = cc ^ ((rr >> 1) & 3);
    const long aoff0 = (long)(row0 + rr) * lda + gg * 8;
    const long aoff1 = (long)(row0 + 64 + rr) * lda + gg * 8;
    const long boff0 = (long)(col0 + rr) * ldb + gg * 8;
    const long boff1 = (long)(col0 + 64 + rr) * ldb + gg * 8;
    const int ldsW = wave * 512;                   // 1KB per wave (ushort units)

    f32x4 acc[4][4];
    #pragma unroll
    for (int m = 0; m < 4; m++)
        #pragma unroll
        for (int n = 0; n < 4; n++)
            acc[m][n] = (f32x4){0.f, 0.f, 0.f, 0.f};

    const int lr = lane & 15, lg = lane >> 4;
    const int wm = (wave >> 1) * 64, wn = (wave & 1) * 64;

    for (int k0 = 0; k0 < K; k0 += 32) {
        // ---- stage 4 tiles x 2 halves via global_load_lds (16B/lane) ----
        gload16(Ahi + aoff0 + k0, lAh + 0 * 2048 + ldsW);
        gload16(Ahi + aoff1 + k0, lAh + 1 * 2048 + ldsW);
        gload16(Alo + aoff0 + k0, lAl + 0 * 2048 + ldsW);
        gload16(Alo + aoff1 + k0, lAl + 1 * 2048 + ldsW);
        gload16(Bhi + boff0 + k0, lBh + 0 * 2048 + ldsW);
        gload16(Bhi + boff1 + k0, lBh + 1 * 2048 + ldsW);
        gload16(Blo + boff0 + k0, lBl + 0 * 2048 + ldsW);
        gload16(Blo + boff1 + k0, lBl + 1 * 2048 + ldsW);
        __syncthreads();

        // ---- MFMA phase: 16 + 32 ds_read_b128, 48 MFMAs per wave ----
        short8 ah[4], al[4];
        #pragma unroll
        for (int m = 0; m < 4; m++) {
            ah[m] = ldfrag(lAh, wm + m * 16 + lr, lg);
            al[m] = ldfrag(lAl, wm + m * 16 + lr, lg);
        }
        #pragma unroll
        for (int n = 0; n < 4; n++) {
            const short8 bh = ldfrag(lBh, wn + n * 16 + lr, lg);
            const short8 bl = ldfrag(lBl, wn + n * 16 + lr, lg);
            #pragma unroll
            for (int m = 0; m < 4; m++) {
                acc[m][n] = __builtin_amdgcn_mfma_f32_16x16x32_bf16(ah[m], bh, acc[m][n], 0, 0, 0);
                acc[m][n] = __builtin_amdgcn_mfma_f32_16x16x32_bf16(ah[m], bl, acc[m][n], 0, 0, 0);
                acc[m][n] = __builtin_amdgcn_mfma_f32_16x16x32_bf16(al[m], bh, acc[m][n], 0, 0, 0);
            }
        }
        __syncthreads();
    }

    // ---- epilogue: C/D layout col=lane&15, row=(lane>>4)*4+reg ----
    #pragma unroll
    for (int m = 0; m < 4; m++) {
        #pragma unroll
        for (int n = 0; n < 4; n++) {
            #pragma unroll
            for (int r = 0; r < 4; r++) {
                const int grow = row0 + wm + m * 16 + lg * 4 + r;
                const int gcol = col0 + wn + n * 16 + lr;
                const float v = alpha * acc[m][n][r];
                const long o = (long)grow * ldc + gcol;
                if (EPI == EP_F32) {
                    Cf[o] = v;
                } else if (EPI == EP_SIG) {
                    Cf[o] = 1.0f / (1.0f + __expf(-v));
                } else {
                    u16 h, l; split2(v, h, l);
                    Chi[o] = h; Clo[o] = l;
                }
            }
        }
    }
}

// float -> (hi,lo) bf16, row-major, 4 elems/thread
__global__ __launch_bounds__(256)
void split_rm(const float* __restrict__ in, u16* __restrict__ hi, u16* __restrict__ lo)
{
    const long i = ((long)blockIdx.x * 256 + threadIdx.x) * 4;
    const float4 v = *reinterpret_cast<const float4*>(in + i);
    ushort4 h, l;
    split2(v.x, h.x, l.x);
    split2(v.y, h.y, l.y);
    split2(v.z, h.z, l.z);
    split2(v.w, h.w, l.w);
    *reinterpret_cast<ushort4*>(hi + i) = h;
    *reinterpret_cast<ushort4*>(lo + i) = l;
}

// float (R x C) -> transposed (C x R) (hi,lo) bf16; batched via blockIdx.z
__global__ __launch_bounds__(256)
void split_tr(const float* __restrict__ in, u16* __restrict__ hi, u16* __restrict__ lo,
              int R, int C, long sIn, long sOut)
{
    in += (long)blockIdx.z * sIn;
    hi += (long)blockIdx.z * sOut;
    lo += (long)blockIdx.z * sOut;

    __shared__ float tile[32][33];
    const int tx = threadIdx.x & 31, ty = threadIdx.x >> 5;   // 32 x 8
    const int r0 = blockIdx.y * 32, c0 = blockIdx.x * 32;

    #pragma unroll
    for (int j = 0; j < 4; j++)
        tile[ty * 4 + j][tx] = in[(long)(r0 + ty * 4 + j) * C + c0 + tx];
    __syncthreads();

    #pragma unroll
    for (int j = 0; j < 4; j++) {
        const int oc = ty * 4 + j;
        const float v = tile[tx][oc];
        u16 h, l; split2(v, h, l);
        const long o = (long)(c0 + oc) * R + r0 + tx;
        hi[o] = h; lo[o] = l;
    }
}

// row softmax over 2048 fp32 logits -> (hi,lo) bf16 probabilities
__global__ __launch_bounds__(256)
void softmax_hilo(const float* __restrict__ S, u16* __restrict__ hi, u16* __restrict__ lo)
{
    const int NC = 2048;
    const long base = (long)blockIdx.x * NC;
    const float* p = S + base;
    const int tid = threadIdx.x;

    float4 v0 = reinterpret_cast<const float4*>(p)[tid];
    float4 v1 = reinterpret_cast<const float4*>(p)[tid + 256];

    float m = fmaxf(fmaxf(fmaxf(v0.x, v0.y), fmaxf(v0.z, v0.w)),
                    fmaxf(fmaxf(v1.x, v1.y), fmaxf(v1.z, v1.w)));
    #pragma unroll
    for (int off = 1; off < 64; off <<= 1)
        m = fmaxf(m, __shfl_xor(m, off));

    __shared__ float redm[4];
    __shared__ float reds[4];
    const int wave = tid >> 6, lane = tid & 63;
    if (lane == 0) redm[wave] = m;
    __syncthreads();
    m = fmaxf(fmaxf(redm[0], redm[1]), fmaxf(redm[2], redm[3]));

    v0.x = __expf(v0.x - m); v0.y = __expf(v0.y - m);
    v0.z = __expf(v0.z - m); v0.w = __expf(v0.w - m);
    v1.x = __expf(v1.x - m); v1.y = __expf(v1.y - m);
    v1.z = __expf(v1.z - m); v1.w = __expf(v1.w - m);

    float s = (v0.x + v0.y + v0.z + v0.w) + (v1.x + v1.y + v1.z + v1.w);
    #pragma unroll
    for (int off = 1; off < 64; off <<= 1)
        s += __shfl_xor(s, off);
    if (lane == 0) reds[wave] = s;
    __syncthreads();
    s = (reds[0] + reds[1]) + (reds[2] + reds[3]);

    const float inv = 1.0f / s;
    ushort4 h0, l0, h1, l1;
    split2(v0.x * inv, h0.x, l0.x); split2(v0.y * inv, h0.y, l0.y);
    split2(v0.z * inv, h0.z, l0.z); split2(v0.w * inv, h0.w, l0.w);
    split2(v1.x * inv, h1.x, l1.x); split2(v1.y * inv, h1.y, l1.y);
    split2(v1.z * inv, h1.z, l1.z); split2(v1.w * inv, h1.w, l1.w);

    reinterpret_cast<ushort4*>(hi + base)[tid]       = h0;
    reinterpret_cast<ushort4*>(hi + base)[tid + 256] = h1;
    reinterpret_cast<ushort4*>(lo + base)[tid]       = l0;
    reinterpret_cast<ushort4*>(lo + base)[tid + 256] = l1;
}

extern "C" void kernel_launch(void* const* d_in, const int* in_sizes, int n_in,
                              void* d_out, int out_size, void* d_ws, size_t ws_size,
                              hipStream_t stream)
{
    (void)in_sizes; (void)n_in; (void)out_size; (void)ws_size;
    const float* X = (const float*)d_in[0];   // (4,2048,1024)
    const float* R = (const float*)d_in[1];   // (1024,1024)
    const float* E = (const float*)d_in[2];   // (1024,1024)
    float* out = (float*)d_out;

    const int B = 4, SQ = 2048, D = 1024;
    const long NDX = (long)B * SQ * D;        // 8388608
    const long DD  = (long)D * D;             // 1048576
    const long SS  = (long)B * SQ * SQ;       // 16777216

    u16* wsu = (u16*)d_ws;
    // Region A: bytes [0, 64MB). Lifetime 1: X/Rt/Et splits. Lifetime 2: S fp32.
    // Lifetime 3: Xt splits.
    u16* Xhi  = wsu;
    u16* Xlo  = Xhi + NDX;
    u16* Rthi = Xlo + NDX;
    u16* Rtlo = Rthi + DD;
    u16* Ethi = Rtlo + DD;
    u16* Etlo = Ethi + DD;                    // ends at 20.97M u16 < 32M
    float* Sf = (float*)d_ws;                 // SS floats = 64MB
    u16* Xthi = wsu;
    u16* Xtlo = Xthi + NDX;
    // Region B: bytes [64MB, 128MB). Lifetime 1: Q/K splits. Lifetime 2: S splits.
    u16* Qhi = wsu + 33554432;
    u16* Qlo = Qhi + NDX;
    u16* Khi = Qlo + NDX;
    u16* Klo = Khi + NDX;
    u16* Shi = wsu + 33554432;
    u16* Slo = Shi + SS;

    dim3 thr(256);

    // split inputs
    split_rm<<<dim3((unsigned)(NDX / 1024)), thr, 0, stream>>>(X, Xhi, Xlo);
    split_tr<<<dim3(32, 32, 1), thr, 0, stream>>>(R, Rthi, Rtlo, D, D, 0, 0);
    split_tr<<<dim3(32, 32, 1), thr, 0, stream>>>(E, Ethi, Etlo, D, D, 0, 0);

    // Q = X @ R, K = X @ E  -> hi/lo
    gemm_split<EP_HILO><<<dim3(D / 128, (B * SQ) / 128, 1), thr, 0, stream>>>(
        Xhi, Xlo, Rthi, Rtlo, nullptr, Qhi, Qlo, D, D, D, D, 0, 0, 0, 1.0f);
    gemm_split<EP_HILO><<<dim3(D / 128, (B * SQ) / 128, 1), thr, 0, stream>>>(
        Xhi, Xlo, Ethi, Etlo, nullptr, Khi, Klo, D, D, D, D, 0, 0, 0, 1.0f);

    // S = Q K^T / 32 (fp32 logits into region A; X/Rt/Et dead)
    gemm_split<EP_F32><<<dim3(SQ / 128, SQ / 128, B), thr, 0, stream>>>(
        Qhi, Qlo, Khi, Klo, Sf, nullptr, nullptr, D, D, D, SQ,
        (long)SQ * D, (long)SQ * D, (long)SQ * SQ, 0.03125f);

    // softmax fp32 -> probability hi/lo into region B (Q/K dead)
    softmax_hilo<<<dim3(B * SQ), thr, 0, stream>>>(Sf, Shi, Slo);

    // Xt (per batch 1024x2048) into region A (S fp32 dead)
    split_tr<<<dim3(D / 32, SQ / 32, B), thr, 0, stream>>>(
        X, Xthi, Xtlo, SQ, D, (long)SQ * D, (long)SQ * D);

    // O = sigmoid(S @ X)
    gemm_split<EP_SIG><<<dim3(D / 128, SQ / 128, B), thr, 0, stream>>>(
        Shi, Slo, Xthi, Xtlo, out, nullptr, nullptr, SQ, SQ, SQ, D,
        (long)SQ * SQ, (long)SQ * D, (long)SQ * D, 1.0f);
}

// Round 3
// 320.926 us; speedup vs baseline: 3.8450x; 1.2377x over previous
//
#include <hip/hip_runtime.h>
#include <hip/hip_bf16.h>
#include <math.h>

// SelfAttentionHybrid via split-bf16 (hi+lo) triple-MFMA fp32 emulation.
//   QK = X @ [R | E]                 (8192x1024 @ 1024x2048, merged)
//   S  = softmax(Q K^T / 32)         (4 x 2048x2048, K=1024, triple-MFMA)
//   O  = sigmoid(S @ X)              (4 x 2048x1024, K=2048, single bf16 MFMA)
// Triple GEMMs: acc += Ahi*Bhi + Ahi*Blo + Alo*Bhi  (lo*lo ~2^-18 dropped).
// PV: S,X near-one-hot / O(1) -> plain bf16 suffices (error ~0.004 in O).

using u16 = unsigned short;
using short8 = __attribute__((ext_vector_type(8))) short;
using f32x4  = __attribute__((ext_vector_type(4))) float;

__device__ static inline u16 f2bf(float f) {
    union { __hip_bfloat16 h; u16 u; } cv; cv.h = __float2bfloat16(f); return cv.u;
}
__device__ static inline float bf2f(u16 u) {
    union { __hip_bfloat16 h; u16 u; } cv; cv.u = u; return __bfloat162float(cv.h);
}
__device__ static inline void split2(float v, u16& h, u16& l) {
    h = f2bf(v);
    l = f2bf(v - bf2f(h));
}

__device__ static inline void gload16(const u16* g, u16* l) {
    __builtin_amdgcn_global_load_lds(
        (const __attribute__((address_space(1))) void*)g,
        (__attribute__((address_space(3))) void*)l, 16, 0, 0);
}

// LDS tile layout: [128 rows][32 bf16], row = 64B. 16B chunk index is
// XOR-swizzled: chunk_stored(c) holds k-group g = c ^ ((row>>1)&3).
// Readers (lanes 0..15 = consecutive rows at fixed k-group) then spread
// across all 32 banks at worst 2-way (free).
__device__ static inline short8 ldfrag(const u16* sm, int row, int g) {
    const int off = row * 32 + ((g ^ ((row >> 1) & 3)) << 3);
    return *reinterpret_cast<const short8*>(sm + off);
}

enum { EP_F32 = 0, EP_HILO = 1, EP_SIG = 2 };

template<int EPI, bool TRIPLE>
__global__ __launch_bounds__(256)
void gemm_split(const u16* __restrict__ Ahi, const u16* __restrict__ Alo,
                const u16* __restrict__ Bhi, const u16* __restrict__ Blo,
                float* __restrict__ Cf, u16* __restrict__ Chi, u16* __restrict__ Clo,
                int K, int lda, int ldb, int ldc,
                long sA, long sB, long sC, float alpha)
{
    const int z = blockIdx.z;
    Ahi += z * sA;
    Bhi += z * sB;
    if (TRIPLE) { Alo += z * sA; Blo += z * sB; }
    if (EPI == EP_HILO) { Chi += z * sC; Clo += z * sC; }
    else                { Cf  += z * sC; }

    constexpr int NTILE = TRIPLE ? 4 : 2;
    __shared__ __align__(16) u16 smem[NTILE * 4096];
    u16* lAh = &smem[0];
    u16* lBh = &smem[TRIPLE ? 8192 : 4096];
    u16* lAl = TRIPLE ? &smem[4096]  : nullptr;
    u16* lBl = TRIPLE ? &smem[12288] : nullptr;

    const int t = threadIdx.x;
    const int wave = t >> 6, lane = t & 63;
    const int row0 = blockIdx.y * 128, col0 = blockIdx.x * 128;

    // staging: thread t owns LDS slot (row = h*64 + t/4, chunk = t&3);
    // fetch the global k-group that the swizzle stores there.
    const int rr = t >> 2, cc = t & 3;
    const int gg = cc ^ ((rr >> 1) & 3);
    const long aoff0 = (long)(row0 + rr) * lda + gg * 8;
    const long aoff1 = (long)(row0 + 64 + rr) * lda + gg * 8;
    const long boff0 = (long)(col0 + rr) * ldb + gg * 8;
    const long boff1 = (long)(col0 + 64 + rr) * ldb + gg * 8;
    const int ldsW = wave * 512;                   // 1KB per wave (ushort units)

    f32x4 acc[4][4];
    #pragma unroll
    for (int m = 0; m < 4; m++)
        #pragma unroll
        for (int n = 0; n < 4; n++)
            acc[m][n] = (f32x4){0.f, 0.f, 0.f, 0.f};

    const int lr = lane & 15, lg = lane >> 4;
    const int wm = (wave >> 1) * 64, wn = (wave & 1) * 64;

    for (int k0 = 0; k0 < K; k0 += 32) {
        // ---- stage tiles via global_load_lds (16B/lane) ----
        gload16(Ahi + aoff0 + k0, lAh + 0 * 2048 + ldsW);
        gload16(Ahi + aoff1 + k0, lAh + 1 * 2048 + ldsW);
        gload16(Bhi + boff0 + k0, lBh + 0 * 2048 + ldsW);
        gload16(Bhi + boff1 + k0, lBh + 1 * 2048 + ldsW);
        if (TRIPLE) {
            gload16(Alo + aoff0 + k0, lAl + 0 * 2048 + ldsW);
            gload16(Alo + aoff1 + k0, lAl + 1 * 2048 + ldsW);
            gload16(Blo + boff0 + k0, lBl + 0 * 2048 + ldsW);
            gload16(Blo + boff1 + k0, lBl + 1 * 2048 + ldsW);
        }
        __syncthreads();

        // ---- MFMA phase ----
        short8 ah[4], al[4];
        #pragma unroll
        for (int m = 0; m < 4; m++) {
            ah[m] = ldfrag(lAh, wm + m * 16 + lr, lg);
            if (TRIPLE) al[m] = ldfrag(lAl, wm + m * 16 + lr, lg);
        }
        #pragma unroll
        for (int n = 0; n < 4; n++) {
            const short8 bh = ldfrag(lBh, wn + n * 16 + lr, lg);
            short8 bl;
            if (TRIPLE) bl = ldfrag(lBl, wn + n * 16 + lr, lg);
            #pragma unroll
            for (int m = 0; m < 4; m++) {
                acc[m][n] = __builtin_amdgcn_mfma_f32_16x16x32_bf16(ah[m], bh, acc[m][n], 0, 0, 0);
                if (TRIPLE) {
                    acc[m][n] = __builtin_amdgcn_mfma_f32_16x16x32_bf16(ah[m], bl, acc[m][n], 0, 0, 0);
                    acc[m][n] = __builtin_amdgcn_mfma_f32_16x16x32_bf16(al[m], bh, acc[m][n], 0, 0, 0);
                }
            }
        }
        __syncthreads();
    }

    // ---- epilogue: C/D layout col=lane&15, row=(lane>>4)*4+reg ----
    #pragma unroll
    for (int m = 0; m < 4; m++) {
        #pragma unroll
        for (int n = 0; n < 4; n++) {
            #pragma unroll
            for (int r = 0; r < 4; r++) {
                const int grow = row0 + wm + m * 16 + lg * 4 + r;
                const int gcol = col0 + wn + n * 16 + lr;
                const float v = alpha * acc[m][n][r];
                const long o = (long)grow * ldc + gcol;
                if (EPI == EP_F32) {
                    Cf[o] = v;
                } else if (EPI == EP_SIG) {
                    Cf[o] = 1.0f / (1.0f + __expf(-v));
                } else {
                    u16 h, l; split2(v, h, l);
                    Chi[o] = h; Clo[o] = l;
                }
            }
        }
    }
}

// float -> (hi,lo) bf16, row-major, 4 elems/thread
__global__ __launch_bounds__(256)
void split_rm(const float* __restrict__ in, u16* __restrict__ hi, u16* __restrict__ lo)
{
    const long i = ((long)blockIdx.x * 256 + threadIdx.x) * 4;
    const float4 v = *reinterpret_cast<const float4*>(in + i);
    ushort4 h, l;
    split2(v.x, h.x, l.x);
    split2(v.y, h.y, l.y);
    split2(v.z, h.z, l.z);
    split2(v.w, h.w, l.w);
    *reinterpret_cast<ushort4*>(hi + i) = h;
    *reinterpret_cast<ushort4*>(lo + i) = l;
}

// float (R x C) -> transposed (C x R) bf16 hi (+lo if HILO); batched via blockIdx.z
template<bool HILO>
__global__ __launch_bounds__(256)
void split_tr(const float* __restrict__ in, u16* __restrict__ hi, u16* __restrict__ lo,
              int R, int C, long sIn, long sOut)
{
    in += (long)blockIdx.z * sIn;
    hi += (long)blockIdx.z * sOut;
    if (HILO) lo += (long)blockIdx.z * sOut;

    __shared__ float tile[32][33];
    const int tx = threadIdx.x & 31, ty = threadIdx.x >> 5;   // 32 x 8
    const int r0 = blockIdx.y * 32, c0 = blockIdx.x * 32;

    #pragma unroll
    for (int j = 0; j < 4; j++)
        tile[ty * 4 + j][tx] = in[(long)(r0 + ty * 4 + j) * C + c0 + tx];
    __syncthreads();

    #pragma unroll
    for (int j = 0; j < 4; j++) {
        const int oc = ty * 4 + j;
        const float v = tile[tx][oc];
        u16 h, l; split2(v, h, l);
        const long o = (long)(c0 + oc) * R + r0 + tx;
        hi[o] = h;
        if (HILO) lo[o] = l;
    }
}

// row softmax over 2048 fp32 logits -> bf16 (hi only) probabilities
__global__ __launch_bounds__(256)
void softmax_hi(const float* __restrict__ S, u16* __restrict__ hi)
{
    const int NC = 2048;
    const long base = (long)blockIdx.x * NC;
    const float* p = S + base;
    const int tid = threadIdx.x;

    float4 v0 = reinterpret_cast<const float4*>(p)[tid];
    float4 v1 = reinterpret_cast<const float4*>(p)[tid + 256];

    float m = fmaxf(fmaxf(fmaxf(v0.x, v0.y), fmaxf(v0.z, v0.w)),
                    fmaxf(fmaxf(v1.x, v1.y), fmaxf(v1.z, v1.w)));
    #pragma unroll
    for (int off = 1; off < 64; off <<= 1)
        m = fmaxf(m, __shfl_xor(m, off));

    __shared__ float redm[4];
    __shared__ float reds[4];
    const int wave = tid >> 6, lane = tid & 63;
    if (lane == 0) redm[wave] = m;
    __syncthreads();
    m = fmaxf(fmaxf(redm[0], redm[1]), fmaxf(redm[2], redm[3]));

    v0.x = __expf(v0.x - m); v0.y = __expf(v0.y - m);
    v0.z = __expf(v0.z - m); v0.w = __expf(v0.w - m);
    v1.x = __expf(v1.x - m); v1.y = __expf(v1.y - m);
    v1.z = __expf(v1.z - m); v1.w = __expf(v1.w - m);

    float s = (v0.x + v0.y + v0.z + v0.w) + (v1.x + v1.y + v1.z + v1.w);
    #pragma unroll
    for (int off = 1; off < 64; off <<= 1)
        s += __shfl_xor(s, off);
    if (lane == 0) reds[wave] = s;
    __syncthreads();
    s = (reds[0] + reds[1]) + (reds[2] + reds[3]);

    const float inv = 1.0f / s;
    ushort4 h0, h1;
    h0.x = f2bf(v0.x * inv); h0.y = f2bf(v0.y * inv);
    h0.z = f2bf(v0.z * inv); h0.w = f2bf(v0.w * inv);
    h1.x = f2bf(v1.x * inv); h1.y = f2bf(v1.y * inv);
    h1.z = f2bf(v1.z * inv); h1.w = f2bf(v1.w * inv);

    reinterpret_cast<ushort4*>(hi + base)[tid]       = h0;
    reinterpret_cast<ushort4*>(hi + base)[tid + 256] = h1;
}

extern "C" void kernel_launch(void* const* d_in, const int* in_sizes, int n_in,
                              void* d_out, int out_size, void* d_ws, size_t ws_size,
                              hipStream_t stream)
{
    (void)in_sizes; (void)n_in; (void)out_size; (void)ws_size;
    const float* X = (const float*)d_in[0];   // (4,2048,1024)
    const float* R = (const float*)d_in[1];   // (1024,1024)
    const float* E = (const float*)d_in[2];   // (1024,1024)
    float* out = (float*)d_out;

    const int B = 4, SQ = 2048, D = 1024;
    const long NDX = (long)B * SQ * D;        // 8388608
    const long DD  = (long)D * D;             // 1048576
    const long SS  = (long)B * SQ * SQ;       // 16777216

    u16* wsu = (u16*)d_ws;
    // Region A: bytes [0, 64MB).
    //   Phase 1: Xhi/Xlo (16MB each) + RtEt hi/lo (4MB each) = 40MB.
    //   Phase 2: Sf fp32 (64MB).  Phase 3: Xthi (16MB).
    u16* Xhi    = wsu;
    u16* Xlo    = Xhi + NDX;
    u16* RtEthi = Xlo + NDX;                  // (2048 x 1024): rows 0-1023 = R^T, 1024-2047 = E^T
    u16* RtEtlo = RtEthi + 2 * DD;
    float* Sf   = (float*)d_ws;               // SS floats = 64MB
    u16* Xthi   = wsu;                        // (4 x 1024 x 2048)
    // Region B: bytes [64MB, 128MB).
    //   Phase 1: QKhi/QKlo (8192 x 2048 each = 32MB each).  Phase 2: Shi (32MB).
    u16* QKhi = wsu + 33554432;
    u16* QKlo = QKhi + (NDX * 2);
    u16* Shi  = wsu + 33554432;

    dim3 thr(256);

    // split inputs
    split_rm<<<dim3((unsigned)(NDX / 1024)), thr, 0, stream>>>(X, Xhi, Xlo);
    split_tr<true><<<dim3(32, 32, 1), thr, 0, stream>>>(R, RtEthi, RtEtlo, D, D, 0, 0);
    split_tr<true><<<dim3(32, 32, 1), thr, 0, stream>>>(E, RtEthi + DD, RtEtlo + DD, D, D, 0, 0);

    // QK = X @ [R | E]  -> hi/lo, C is (8192 x 2048), cols 0-1023 = Q, 1024-2047 = K
    gemm_split<EP_HILO, true><<<dim3(2 * D / 128, (B * SQ) / 128, 1), thr, 0, stream>>>(
        Xhi, Xlo, RtEthi, RtEtlo, nullptr, QKhi, QKlo,
        D, D, D, 2 * D, 0, 0, 0, 1.0f);

    // S = Q K^T / 32 (fp32 logits into region A; X/RtEt dead)
    gemm_split<EP_F32, true><<<dim3(SQ / 128, SQ / 128, B), thr, 0, stream>>>(
        QKhi, QKlo, QKhi + D, QKlo + D, Sf, nullptr, nullptr,
        D, 2 * D, 2 * D, SQ,
        (long)SQ * 2 * D, (long)SQ * 2 * D, (long)SQ * SQ, 0.03125f);

    // softmax fp32 -> probability hi into region B (QK dead)
    softmax_hi<<<dim3(B * SQ), thr, 0, stream>>>(Sf, Shi);

    // Xt (per batch 1024x2048) hi-only into region A (Sf dead)
    split_tr<false><<<dim3(D / 32, SQ / 32, B), thr, 0, stream>>>(
        X, Xthi, nullptr, SQ, D, (long)SQ * D, (long)SQ * D);

    // O = sigmoid(S @ X), single-bf16 MFMA
    gemm_split<EP_SIG, false><<<dim3(D / 128, SQ / 128, B), thr, 0, stream>>>(
        Shi, nullptr, Xthi, nullptr, out, nullptr, nullptr,
        SQ, SQ, SQ, D,
        (long)SQ * SQ, (long)SQ * D, (long)SQ * D, 1.0f);
}

// Round 4
// 290.354 us; speedup vs baseline: 4.2498x; 1.1053x over previous
//
#include <hip/hip_runtime.h>
#include <hip/hip_bf16.h>
#include <math.h>

// SelfAttentionHybrid via split-bf16 (hi+lo) triple-MFMA fp32 emulation,
// using the algebraic rewrite  QK^T = X (R E^T) X^T:
//   Wt = E @ R^T           (1024^3, K-split x4 + reduce; Wt = (R E^T)^T)
//   Y  = X @ (Wt)^T = X R E^T        (8192x1024x1024, triple)
//   S  = softmax(Y X^T / 32)         (4 x 2048x2048, K=1024, triple; B = X as stored)
//   O  = sigmoid(S @ X)              (4 x 2048x1024, K=2048, single bf16 MFMA)
// Triple GEMMs: acc += Ahi*Bhi + Ahi*Blo + Alo*Bhi  (lo*lo ~2^-18 dropped).

using u16 = unsigned short;
using short8 = __attribute__((ext_vector_type(8))) short;
using f32x4  = __attribute__((ext_vector_type(4))) float;

__device__ static inline u16 f2bf(float f) {
    union { __hip_bfloat16 h; u16 u; } cv; cv.h = __float2bfloat16(f); return cv.u;
}
__device__ static inline float bf2f(u16 u) {
    union { __hip_bfloat16 h; u16 u; } cv; cv.u = u; return __bfloat162float(cv.h);
}
__device__ static inline void split2(float v, u16& h, u16& l) {
    h = f2bf(v);
    l = f2bf(v - bf2f(h));
}

__device__ static inline void gload16(const u16* g, u16* l) {
    __builtin_amdgcn_global_load_lds(
        (const __attribute__((address_space(1))) void*)g,
        (__attribute__((address_space(3))) void*)l, 16, 0, 0);
}

// LDS tile layout: [128 rows][32 bf16], row = 64B. 16B chunk index is
// XOR-swizzled: chunk_stored(c) holds k-group g = c ^ ((row>>1)&3).
__device__ static inline short8 ldfrag(const u16* sm, int row, int g) {
    const int off = row * 32 + ((g ^ ((row >> 1) & 3)) << 3);
    return *reinterpret_cast<const short8*>(sm + off);
}

enum { EP_F32 = 0, EP_HILO = 1, EP_SIG = 2 };

template<int EPI, bool TRIPLE>
__global__ __launch_bounds__(256)
void gemm_split(const u16* __restrict__ Ahi, const u16* __restrict__ Alo,
                const u16* __restrict__ Bhi, const u16* __restrict__ Blo,
                float* __restrict__ Cf, u16* __restrict__ Chi, u16* __restrict__ Clo,
                int K, int lda, int ldb, int ldc,
                long sA, long sB, long sC, float alpha)
{
    const int z = blockIdx.z;
    Ahi += z * sA;
    Bhi += z * sB;
    if (TRIPLE) { Alo += z * sA; Blo += z * sB; }
    if (EPI == EP_HILO) { Chi += z * sC; Clo += z * sC; }
    else                { Cf  += z * sC; }

    constexpr int NTILE = TRIPLE ? 4 : 2;
    __shared__ __align__(16) u16 smem[NTILE * 4096];
    u16* lAh = &smem[0];
    u16* lBh = &smem[TRIPLE ? 8192 : 4096];
    u16* lAl = TRIPLE ? &smem[4096]  : nullptr;
    u16* lBl = TRIPLE ? &smem[12288] : nullptr;

    const int t = threadIdx.x;
    const int wave = t >> 6, lane = t & 63;
    const int row0 = blockIdx.y * 128, col0 = blockIdx.x * 128;

    const int rr = t >> 2, cc = t & 3;
    const int gg = cc ^ ((rr >> 1) & 3);
    const long aoff0 = (long)(row0 + rr) * lda + gg * 8;
    const long aoff1 = (long)(row0 + 64 + rr) * lda + gg * 8;
    const long boff0 = (long)(col0 + rr) * ldb + gg * 8;
    const long boff1 = (long)(col0 + 64 + rr) * ldb + gg * 8;
    const int ldsW = wave * 512;                   // 1KB per wave (ushort units)

    f32x4 acc[4][4];
    #pragma unroll
    for (int m = 0; m < 4; m++)
        #pragma unroll
        for (int n = 0; n < 4; n++)
            acc[m][n] = (f32x4){0.f, 0.f, 0.f, 0.f};

    const int lr = lane & 15, lg = lane >> 4;
    const int wm = (wave >> 1) * 64, wn = (wave & 1) * 64;

    for (int k0 = 0; k0 < K; k0 += 32) {
        gload16(Ahi + aoff0 + k0, lAh + 0 * 2048 + ldsW);
        gload16(Ahi + aoff1 + k0, lAh + 1 * 2048 + ldsW);
        gload16(Bhi + boff0 + k0, lBh + 0 * 2048 + ldsW);
        gload16(Bhi + boff1 + k0, lBh + 1 * 2048 + ldsW);
        if (TRIPLE) {
            gload16(Alo + aoff0 + k0, lAl + 0 * 2048 + ldsW);
            gload16(Alo + aoff1 + k0, lAl + 1 * 2048 + ldsW);
            gload16(Blo + boff0 + k0, lBl + 0 * 2048 + ldsW);
            gload16(Blo + boff1 + k0, lBl + 1 * 2048 + ldsW);
        }
        __syncthreads();

        short8 ah[4], al[4];
        #pragma unroll
        for (int m = 0; m < 4; m++) {
            ah[m] = ldfrag(lAh, wm + m * 16 + lr, lg);
            if (TRIPLE) al[m] = ldfrag(lAl, wm + m * 16 + lr, lg);
        }
        #pragma unroll
        for (int n = 0; n < 4; n++) {
            const short8 bh = ldfrag(lBh, wn + n * 16 + lr, lg);
            short8 bl;
            if (TRIPLE) bl = ldfrag(lBl, wn + n * 16 + lr, lg);
            #pragma unroll
            for (int m = 0; m < 4; m++) {
                acc[m][n] = __builtin_amdgcn_mfma_f32_16x16x32_bf16(ah[m], bh, acc[m][n], 0, 0, 0);
                if (TRIPLE) {
                    acc[m][n] = __builtin_amdgcn_mfma_f32_16x16x32_bf16(ah[m], bl, acc[m][n], 0, 0, 0);
                    acc[m][n] = __builtin_amdgcn_mfma_f32_16x16x32_bf16(al[m], bh, acc[m][n], 0, 0, 0);
                }
            }
        }
        __syncthreads();
    }

    // ---- epilogue: C/D layout col=lane&15, row=(lane>>4)*4+reg ----
    #pragma unroll
    for (int m = 0; m < 4; m++) {
        #pragma unroll
        for (int n = 0; n < 4; n++) {
            #pragma unroll
            for (int r = 0; r < 4; r++) {
                const int grow = row0 + wm + m * 16 + lg * 4 + r;
                const int gcol = col0 + wn + n * 16 + lr;
                const float v = alpha * acc[m][n][r];
                const long o = (long)grow * ldc + gcol;
                if (EPI == EP_F32) {
                    Cf[o] = v;
                } else if (EPI == EP_SIG) {
                    Cf[o] = 1.0f / (1.0f + __expf(-v));
                } else {
                    u16 h, l; split2(v, h, l);
                    Chi[o] = h; Clo[o] = l;
                }
            }
        }
    }
}

// float -> (hi,lo) bf16, row-major, 4 elems/thread
__global__ __launch_bounds__(256)
void split_rm(const float* __restrict__ in, u16* __restrict__ hi, u16* __restrict__ lo)
{
    const long i = ((long)blockIdx.x * 256 + threadIdx.x) * 4;
    const float4 v = *reinterpret_cast<const float4*>(in + i);
    ushort4 h, l;
    split2(v.x, h.x, l.x);
    split2(v.y, h.y, l.y);
    split2(v.z, h.z, l.z);
    split2(v.w, h.w, l.w);
    *reinterpret_cast<ushort4*>(hi + i) = h;
    *reinterpret_cast<ushort4*>(lo + i) = l;
}

// sum 4 partial fp32 buffers (stride n) -> (hi,lo) bf16
__global__ __launch_bounds__(256)
void reduce4_split(const float* __restrict__ p, u16* __restrict__ hi, u16* __restrict__ lo,
                   long n)
{
    const long i = ((long)blockIdx.x * 256 + threadIdx.x) * 4;
    const float4 a = *reinterpret_cast<const float4*>(p + i);
    const float4 b = *reinterpret_cast<const float4*>(p + n + i);
    const float4 c = *reinterpret_cast<const float4*>(p + 2 * n + i);
    const float4 d = *reinterpret_cast<const float4*>(p + 3 * n + i);
    ushort4 h, l;
    split2((a.x + b.x) + (c.x + d.x), h.x, l.x);
    split2((a.y + b.y) + (c.y + d.y), h.y, l.y);
    split2((a.z + b.z) + (c.z + d.z), h.z, l.z);
    split2((a.w + b.w) + (c.w + d.w), h.w, l.w);
    *reinterpret_cast<ushort4*>(hi + i) = h;
    *reinterpret_cast<ushort4*>(lo + i) = l;
}

// float (R x C) -> transposed (C x R) bf16 hi (+lo if HILO); batched via blockIdx.z
template<bool HILO>
__global__ __launch_bounds__(256)
void split_tr(const float* __restrict__ in, u16* __restrict__ hi, u16* __restrict__ lo,
              int R, int C, long sIn, long sOut)
{
    in += (long)blockIdx.z * sIn;
    hi += (long)blockIdx.z * sOut;
    if (HILO) lo += (long)blockIdx.z * sOut;

    __shared__ float tile[32][33];
    const int tx = threadIdx.x & 31, ty = threadIdx.x >> 5;   // 32 x 8
    const int r0 = blockIdx.y * 32, c0 = blockIdx.x * 32;

    #pragma unroll
    for (int j = 0; j < 4; j++)
        tile[ty * 4 + j][tx] = in[(long)(r0 + ty * 4 + j) * C + c0 + tx];
    __syncthreads();

    #pragma unroll
    for (int j = 0; j < 4; j++) {
        const int oc = ty * 4 + j;
        const float v = tile[tx][oc];
        u16 h, l; split2(v, h, l);
        const long o = (long)(c0 + oc) * R + r0 + tx;
        hi[o] = h;
        if (HILO) lo[o] = l;
    }
}

// row softmax over 2048 fp32 logits -> bf16 (hi only) probabilities
__global__ __launch_bounds__(256)
void softmax_hi(const float* __restrict__ S, u16* __restrict__ hi)
{
    const int NC = 2048;
    const long base = (long)blockIdx.x * NC;
    const float* p = S + base;
    const int tid = threadIdx.x;

    float4 v0 = reinterpret_cast<const float4*>(p)[tid];
    float4 v1 = reinterpret_cast<const float4*>(p)[tid + 256];

    float m = fmaxf(fmaxf(fmaxf(v0.x, v0.y), fmaxf(v0.z, v0.w)),
                    fmaxf(fmaxf(v1.x, v1.y), fmaxf(v1.z, v1.w)));
    #pragma unroll
    for (int off = 1; off < 64; off <<= 1)
        m = fmaxf(m, __shfl_xor(m, off));

    __shared__ float redm[4];
    __shared__ float reds[4];
    const int wave = tid >> 6, lane = tid & 63;
    if (lane == 0) redm[wave] = m;
    __syncthreads();
    m = fmaxf(fmaxf(redm[0], redm[1]), fmaxf(redm[2], redm[3]));

    v0.x = __expf(v0.x - m); v0.y = __expf(v0.y - m);
    v0.z = __expf(v0.z - m); v0.w = __expf(v0.w - m);
    v1.x = __expf(v1.x - m); v1.y = __expf(v1.y - m);
    v1.z = __expf(v1.z - m); v1.w = __expf(v1.w - m);

    float s = (v0.x + v0.y + v0.z + v0.w) + (v1.x + v1.y + v1.z + v1.w);
    #pragma unroll
    for (int off = 1; off < 64; off <<= 1)
        s += __shfl_xor(s, off);
    if (lane == 0) reds[wave] = s;
    __syncthreads();
    s = (reds[0] + reds[1]) + (reds[2] + reds[3]);

    const float inv = 1.0f / s;
    ushort4 h0, h1;
    h0.x = f2bf(v0.x * inv); h0.y = f2bf(v0.y * inv);
    h0.z = f2bf(v0.z * inv); h0.w = f2bf(v0.w * inv);
    h1.x = f2bf(v1.x * inv); h1.y = f2bf(v1.y * inv);
    h1.z = f2bf(v1.z * inv); h1.w = f2bf(v1.w * inv);

    reinterpret_cast<ushort4*>(hi + base)[tid]       = h0;
    reinterpret_cast<ushort4*>(hi + base)[tid + 256] = h1;
}

extern "C" void kernel_launch(void* const* d_in, const int* in_sizes, int n_in,
                              void* d_out, int out_size, void* d_ws, size_t ws_size,
                              hipStream_t stream)
{
    (void)in_sizes; (void)n_in; (void)out_size; (void)ws_size;
    const float* X = (const float*)d_in[0];   // (4,2048,1024)
    const float* R = (const float*)d_in[1];   // (1024,1024)
    const float* E = (const float*)d_in[2];   // (1024,1024)
    float* out = (float*)d_out;

    const int B = 4, SQ = 2048, D = 1024;
    const long NDX = (long)B * SQ * D;        // 8388608
    const long DD  = (long)D * D;             // 1048576
    const long SS  = (long)B * SQ * SQ;       // 16777216
    const long M16 = 8388608;                 // u16 elems per 16 MiB

    u16* wsu = (u16*)d_ws;
    // [0,32MB):  Xhi(16) Xlo(16)      -> after S-gemm: Xthi at [0,16)
    // [32,64MB): Rhi Rlo Ehi Elo (8)  -> Yhi(16) Ylo(16) -> Shi(32)
    // [64,128MB): Wpart(16) Wthi/Wtlo(4, at 80MB) -> Sf(64)
    u16* Xhi  = wsu;
    u16* Xlo  = Xhi + NDX;
    u16* Rhi  = wsu + 2 * M16;                // 32MB
    u16* Rlo  = Rhi + DD;
    u16* Ehi  = Rlo + DD;
    u16* Elo  = Ehi + DD;
    u16* Yhi  = wsu + 2 * M16;                // 32MB (R/E dead by then)
    u16* Ylo  = Yhi + NDX;
    u16* Shi  = wsu + 2 * M16;                // 32MB (Y dead by then)
    u16* Xthi = wsu;                          // (X splits dead by then)
    float* Wpart = (float*)(wsu + 4 * M16);   // 64MB: 4 x DD fp32 = 16MB
    u16* Wthi = wsu + 5 * M16;                // 80MB
    u16* Wtlo = Wthi + DD;
    float* Sf = (float*)(wsu + 4 * M16);      // 64MB..128MB (Wpart/Wt dead)

    dim3 thr(256);

    // split inputs (row-major; NT-form GEMMs below need no transposes)
    split_rm<<<dim3((unsigned)(NDX / 1024)), thr, 0, stream>>>(X, Xhi, Xlo);
    split_rm<<<dim3((unsigned)(DD / 1024)), thr, 0, stream>>>(R, Rhi, Rlo);
    split_rm<<<dim3((unsigned)(DD / 1024)), thr, 0, stream>>>(E, Ehi, Elo);

    // Wt = E @ R^T  (= (R E^T)^T), K-split x4 into fp32 partials
    gemm_split<EP_F32, true><<<dim3(D / 128, D / 128, 4), thr, 0, stream>>>(
        Ehi, Elo, Rhi, Rlo, Wpart, nullptr, nullptr,
        256, D, D, D, 256, 256, DD, 1.0f);
    reduce4_split<<<dim3((unsigned)(DD / 1024)), thr, 0, stream>>>(Wpart, Wthi, Wtlo, DD);

    // Y = X @ Wt^T = X R E^T  -> hi/lo (8192 x 1024)
    gemm_split<EP_HILO, true><<<dim3(D / 128, (B * SQ) / 128, 1), thr, 0, stream>>>(
        Xhi, Xlo, Wthi, Wtlo, nullptr, Yhi, Ylo,
        D, D, D, D, 0, 0, 0, 1.0f);

    // S = Y X^T / 32 (fp32 logits; B operand is X as stored)
    gemm_split<EP_F32, true><<<dim3(SQ / 128, SQ / 128, B), thr, 0, stream>>>(
        Yhi, Ylo, Xhi, Xlo, Sf, nullptr, nullptr,
        D, D, D, SQ,
        (long)SQ * D, (long)SQ * D, (long)SQ * SQ, 0.03125f);

    // softmax fp32 -> probability hi into Shi (Y dead)
    softmax_hi<<<dim3(B * SQ), thr, 0, stream>>>(Sf, Shi);

    // Xt (per batch 1024x2048) hi-only (X splits dead)
    split_tr<false><<<dim3(D / 32, SQ / 32, B), thr, 0, stream>>>(
        X, Xthi, nullptr, SQ, D, (long)SQ * D, (long)SQ * D);

    // O = sigmoid(S @ X), single-bf16 MFMA
    gemm_split<EP_SIG, false><<<dim3(D / 128, SQ / 128, B), thr, 0, stream>>>(
        Shi, nullptr, Xthi, nullptr, out, nullptr, nullptr,
        SQ, SQ, SQ, D,
        (long)SQ * SQ, (long)SQ * D, (long)SQ * D, 1.0f);
}

// Round 5
// 273.609 us; speedup vs baseline: 4.5099x; 1.0612x over previous
//
#include <hip/hip_runtime.h>
#include <hip/hip_bf16.h>
#include <math.h>

// SelfAttentionHybrid via split-bf16 (hi+lo) triple-MFMA fp32 emulation,
// using the algebraic rewrite  QK^T = X (R E^T) X^T:
//   Wt = E @ R^T           (1024^3, K-split x4 + reduce; Wt = (R E^T)^T)
//   Y  = X @ (Wt)^T = X R E^T        (8192x1024x1024, triple)
//   S  = softmax(Y X^T / 32)         (4 x 2048x2048, K=1024, triple, 8-phase 256^2)
//   O  = sigmoid(S @ X)              (4 x 2048x1024, K=2048, single bf16 MFMA)
// Triple GEMMs: acc += Ahi*Bhi + Ahi*Blo + Alo*Bhi  (lo*lo ~2^-18 dropped).

using u16 = unsigned short;
using short8 = __attribute__((ext_vector_type(8))) short;
using f32x4  = __attribute__((ext_vector_type(4))) float;

#define MFB(a, b, c) __builtin_amdgcn_mfma_f32_16x16x32_bf16((a), (b), (c), 0, 0, 0)

__device__ static inline u16 f2bf(float f) {
    union { __hip_bfloat16 h; u16 u; } cv; cv.h = __float2bfloat16(f); return cv.u;
}
__device__ static inline float bf2f(u16 u) {
    union { __hip_bfloat16 h; u16 u; } cv; cv.u = u; return __bfloat162float(cv.h);
}
__device__ static inline void split2(float v, u16& h, u16& l) {
    h = f2bf(v);
    l = f2bf(v - bf2f(h));
}

__device__ static inline void gload16(const u16* g, u16* l) {
    __builtin_amdgcn_global_load_lds(
        (const __attribute__((address_space(1))) void*)g,
        (__attribute__((address_space(3))) void*)l, 16, 0, 0);
}

// LDS tile layout: [rows][32 bf16], row = 64B. 16B chunk index is
// XOR-swizzled: chunk slot c holds k-group g = c ^ ((row>>1)&3).
__device__ static inline short8 ldfrag(const u16* sm, int row, int g) {
    const int off = row * 32 + ((g ^ ((row >> 1) & 3)) << 3);
    return *reinterpret_cast<const short8*>(sm + off);
}

enum { EP_F32 = 0, EP_HILO = 1, EP_SIG = 2 };

// ---------------------------------------------------------------------------
// m97-structure 128^2 kernel (W, Y, PV)
// ---------------------------------------------------------------------------
template<int EPI, bool TRIPLE>
__global__ __launch_bounds__(256)
void gemm_split(const u16* __restrict__ Ahi, const u16* __restrict__ Alo,
                const u16* __restrict__ Bhi, const u16* __restrict__ Blo,
                float* __restrict__ Cf, u16* __restrict__ Chi, u16* __restrict__ Clo,
                int K, int lda, int ldb, int ldc,
                long sA, long sB, long sC, float alpha)
{
    const int z = blockIdx.z;
    Ahi += z * sA;
    Bhi += z * sB;
    if (TRIPLE) { Alo += z * sA; Blo += z * sB; }
    if (EPI == EP_HILO) { Chi += z * sC; Clo += z * sC; }
    else                { Cf  += z * sC; }

    constexpr int NTILE = TRIPLE ? 4 : 2;
    __shared__ __align__(16) u16 smem[NTILE * 4096];
    u16* lAh = &smem[0];
    u16* lBh = &smem[TRIPLE ? 8192 : 4096];
    u16* lAl = TRIPLE ? &smem[4096]  : nullptr;
    u16* lBl = TRIPLE ? &smem[12288] : nullptr;

    const int t = threadIdx.x;
    const int wave = t >> 6, lane = t & 63;
    const int row0 = blockIdx.y * 128, col0 = blockIdx.x * 128;

    const int rr = t >> 2, cc = t & 3;
    const int gg = cc ^ ((rr >> 1) & 3);
    const long aoff0 = (long)(row0 + rr) * lda + gg * 8;
    const long aoff1 = (long)(row0 + 64 + rr) * lda + gg * 8;
    const long boff0 = (long)(col0 + rr) * ldb + gg * 8;
    const long boff1 = (long)(col0 + 64 + rr) * ldb + gg * 8;
    const int ldsW = wave * 512;

    f32x4 acc[4][4];
    #pragma unroll
    for (int m = 0; m < 4; m++)
        #pragma unroll
        for (int n = 0; n < 4; n++)
            acc[m][n] = (f32x4){0.f, 0.f, 0.f, 0.f};

    const int lr = lane & 15, lg = lane >> 4;
    const int wm = (wave >> 1) * 64, wn = (wave & 1) * 64;

    for (int k0 = 0; k0 < K; k0 += 32) {
        gload16(Ahi + aoff0 + k0, lAh + 0 * 2048 + ldsW);
        gload16(Ahi + aoff1 + k0, lAh + 1 * 2048 + ldsW);
        gload16(Bhi + boff0 + k0, lBh + 0 * 2048 + ldsW);
        gload16(Bhi + boff1 + k0, lBh + 1 * 2048 + ldsW);
        if (TRIPLE) {
            gload16(Alo + aoff0 + k0, lAl + 0 * 2048 + ldsW);
            gload16(Alo + aoff1 + k0, lAl + 1 * 2048 + ldsW);
            gload16(Blo + boff0 + k0, lBl + 0 * 2048 + ldsW);
            gload16(Blo + boff1 + k0, lBl + 1 * 2048 + ldsW);
        }
        __syncthreads();

        short8 ah[4], al[4];
        #pragma unroll
        for (int m = 0; m < 4; m++) {
            ah[m] = ldfrag(lAh, wm + m * 16 + lr, lg);
            if (TRIPLE) al[m] = ldfrag(lAl, wm + m * 16 + lr, lg);
        }
        #pragma unroll
        for (int n = 0; n < 4; n++) {
            const short8 bh = ldfrag(lBh, wn + n * 16 + lr, lg);
            short8 bl;
            if (TRIPLE) bl = ldfrag(lBl, wn + n * 16 + lr, lg);
            #pragma unroll
            for (int m = 0; m < 4; m++) {
                acc[m][n] = MFB(ah[m], bh, acc[m][n]);
                if (TRIPLE) {
                    acc[m][n] = MFB(ah[m], bl, acc[m][n]);
                    acc[m][n] = MFB(al[m], bh, acc[m][n]);
                }
            }
        }
        __syncthreads();
    }

    #pragma unroll
    for (int m = 0; m < 4; m++) {
        #pragma unroll
        for (int n = 0; n < 4; n++) {
            #pragma unroll
            for (int r = 0; r < 4; r++) {
                const int grow = row0 + wm + m * 16 + lg * 4 + r;
                const int gcol = col0 + wn + n * 16 + lr;
                const float v = alpha * acc[m][n][r];
                const long o = (long)grow * ldc + gcol;
                if (EPI == EP_F32) {
                    Cf[o] = v;
                } else if (EPI == EP_SIG) {
                    Cf[o] = 1.0f / (1.0f + __expf(-v));
                } else {
                    u16 h, l; split2(v, h, l);
                    Chi[o] = h; Clo[o] = l;
                }
            }
        }
    }
}

// ---------------------------------------------------------------------------
// 8-phase 256^2 triple-MFMA kernel (S-gemm). 512 threads / 8 waves (2M x 4N),
// per-wave output 128x64. BK=32. LDS 128 KiB: [2 buf][Ah|Al|Bh|Bl][16KB].
// Per K-tile: 4 phases x {ds_read | gload_lds -> s_barrier -> setprio,
// 24 MFMA -> s_barrier}; one vmcnt(0)+barrier per K-tile (1-deep prefetch).
// ---------------------------------------------------------------------------
__global__ __launch_bounds__(512)
void gemm_triple_8ph(const u16* __restrict__ Ahi, const u16* __restrict__ Alo,
                     const u16* __restrict__ Bhi, const u16* __restrict__ Blo,
                     float* __restrict__ Cf,
                     int K, int lda, int ldb, int ldc,
                     long sA, long sB, long sC, float alpha)
{
    const int z = blockIdx.z;
    Ahi += z * sA; Alo += z * sA;
    Bhi += z * sB; Blo += z * sB;
    Cf  += z * sC;

    __shared__ __align__(16) u16 smem[65536];   // 128 KiB

    const int t = threadIdx.x;
    const int wave = t >> 6, lane = t & 63;
    const int lr = lane & 15, lg = lane >> 4;
    const int row0 = blockIdx.y * 256, col0 = blockIdx.x * 256;
    const int wm = (wave >> 2) * 128, wn = (wave & 3) * 64;

    // staging: thread t owns LDS u16 offset t*8 (+4096 for 2nd round of a tile)
    const int srow = t >> 2;
    const int sg = (t & 3) ^ ((srow >> 1) & 3);
    const u16* gAh = Ahi + (long)(row0 + srow) * lda + sg * 8;
    const u16* gAl = Alo + (long)(row0 + srow) * lda + sg * 8;
    const u16* gBh = Bhi + (long)(col0 + srow) * ldb + sg * 8;
    const u16* gBl = Blo + (long)(col0 + srow) * ldb + sg * 8;
    const long a2 = (long)128 * lda, b2 = (long)128 * ldb;

    f32x4 acc[8][4];
    #pragma unroll
    for (int m = 0; m < 8; m++)
        #pragma unroll
        for (int n = 0; n < 4; n++)
            acc[m][n] = (f32x4){0.f, 0.f, 0.f, 0.f};

    const int NT = K >> 5;

    // prologue: stage K-tile 0 into buf 0
    {
        u16* d = smem + t * 8;
        gload16(gAh,      d);          gload16(gAh + a2, d + 4096);
        gload16(gAl,      d + 8192);   gload16(gAl + a2, d + 12288);
        gload16(gBh,      d + 16384);  gload16(gBh + b2, d + 20480);
        gload16(gBl,      d + 24576);  gload16(gBl + b2, d + 28672);
    }

    short8 ah[4], al[4], bh[2], bl[2];

    for (int tk = 0; tk < NT; ++tk) {
        const int cur = tk & 1;
        const u16* sAh = smem + cur * 32768;
        const u16* sAl = sAh + 8192;
        const u16* sBh = sAh + 16384;
        const u16* sBl = sAh + 24576;
        const bool pf = (tk + 1 < NT);
        const int kn = (tk + 1) << 5;
        u16* d = smem + (cur ^ 1) * 32768 + t * 8;

        // all waves' loads for K-tile tk have landed
        asm volatile("s_waitcnt vmcnt(0)" ::: "memory");
        __builtin_amdgcn_s_barrier();

        // ---- phase 0: m0-3 x n0-1 ----
        #pragma unroll
        for (int mm = 0; mm < 4; mm++) {
            ah[mm] = ldfrag(sAh, wm + mm * 16 + lr, lg);
            al[mm] = ldfrag(sAl, wm + mm * 16 + lr, lg);
        }
        #pragma unroll
        for (int nn = 0; nn < 2; nn++) {
            bh[nn] = ldfrag(sBh, wn + nn * 16 + lr, lg);
            bl[nn] = ldfrag(sBl, wn + nn * 16 + lr, lg);
        }
        if (pf) {
            gload16(gAh + kn,      d);
            gload16(gAh + kn + a2, d + 4096);
            gload16(gAl + kn,      d + 8192);
            gload16(gAl + kn + a2, d + 12288);
        }
        __builtin_amdgcn_s_barrier();
        __builtin_amdgcn_s_setprio(1);
        #pragma unroll
        for (int nn = 0; nn < 2; nn++)
            #pragma unroll
            for (int mm = 0; mm < 4; mm++) {
                acc[mm][nn] = MFB(ah[mm], bh[nn], acc[mm][nn]);
                acc[mm][nn] = MFB(ah[mm], bl[nn], acc[mm][nn]);
                acc[mm][nn] = MFB(al[mm], bh[nn], acc[mm][nn]);
            }
        __builtin_amdgcn_s_setprio(0);
        __builtin_amdgcn_s_barrier();

        // ---- phase 1: m0-3 x n2-3 ----
        #pragma unroll
        for (int nn = 0; nn < 2; nn++) {
            bh[nn] = ldfrag(sBh, wn + (2 + nn) * 16 + lr, lg);
            bl[nn] = ldfrag(sBl, wn + (2 + nn) * 16 + lr, lg);
        }
        if (pf) {
            gload16(gBh + kn,      d + 16384);
            gload16(gBh + kn + b2, d + 20480);
            gload16(gBl + kn,      d + 24576);
            gload16(gBl + kn + b2, d + 28672);
        }
        __builtin_amdgcn_s_barrier();
        __builtin_amdgcn_s_setprio(1);
        #pragma unroll
        for (int nn = 0; nn < 2; nn++)
            #pragma unroll
            for (int mm = 0; mm < 4; mm++) {
                acc[mm][2 + nn] = MFB(ah[mm], bh[nn], acc[mm][2 + nn]);
                acc[mm][2 + nn] = MFB(ah[mm], bl[nn], acc[mm][2 + nn]);
                acc[mm][2 + nn] = MFB(al[mm], bh[nn], acc[mm][2 + nn]);
            }
        __builtin_amdgcn_s_setprio(0);
        __builtin_amdgcn_s_barrier();

        // ---- phase 2: m4-7 x n2-3 ----
        #pragma unroll
        for (int mm = 0; mm < 4; mm++) {
            ah[mm] = ldfrag(sAh, wm + (4 + mm) * 16 + lr, lg);
            al[mm] = ldfrag(sAl, wm + (4 + mm) * 16 + lr, lg);
        }
        __builtin_amdgcn_s_barrier();
        __builtin_amdgcn_s_setprio(1);
        #pragma unroll
        for (int nn = 0; nn < 2; nn++)
            #pragma unroll
            for (int mm = 0; mm < 4; mm++) {
                acc[4 + mm][2 + nn] = MFB(ah[mm], bh[nn], acc[4 + mm][2 + nn]);
                acc[4 + mm][2 + nn] = MFB(ah[mm], bl[nn], acc[4 + mm][2 + nn]);
                acc[4 + mm][2 + nn] = MFB(al[mm], bh[nn], acc[4 + mm][2 + nn]);
            }
        __builtin_amdgcn_s_setprio(0);
        __builtin_amdgcn_s_barrier();

        // ---- phase 3: m4-7 x n0-1 ----
        #pragma unroll
        for (int nn = 0; nn < 2; nn++) {
            bh[nn] = ldfrag(sBh, wn + nn * 16 + lr, lg);
            bl[nn] = ldfrag(sBl, wn + nn * 16 + lr, lg);
        }
        __builtin_amdgcn_s_barrier();
        __builtin_amdgcn_s_setprio(1);
        #pragma unroll
        for (int nn = 0; nn < 2; nn++)
            #pragma unroll
            for (int mm = 0; mm < 4; mm++) {
                acc[4 + mm][nn] = MFB(ah[mm], bh[nn], acc[4 + mm][nn]);
                acc[4 + mm][nn] = MFB(ah[mm], bl[nn], acc[4 + mm][nn]);
                acc[4 + mm][nn] = MFB(al[mm], bh[nn], acc[4 + mm][nn]);
            }
        __builtin_amdgcn_s_setprio(0);
        // phase-3 end barrier folded into next iteration's top barrier
    }

    // ---- epilogue: C/D layout col=lane&15, row=(lane>>4)*4+reg ----
    #pragma unroll
    for (int m = 0; m < 8; m++) {
        #pragma unroll
        for (int n = 0; n < 4; n++) {
            #pragma unroll
            for (int r = 0; r < 4; r++) {
                const int grow = row0 + wm + m * 16 + lg * 4 + r;
                const int gcol = col0 + wn + n * 16 + lr;
                Cf[(long)grow * ldc + gcol] = alpha * acc[m][n][r];
            }
        }
    }
}

// float -> (hi,lo) bf16, row-major, 4 elems/thread
__global__ __launch_bounds__(256)
void split_rm(const float* __restrict__ in, u16* __restrict__ hi, u16* __restrict__ lo)
{
    const long i = ((long)blockIdx.x * 256 + threadIdx.x) * 4;
    const float4 v = *reinterpret_cast<const float4*>(in + i);
    ushort4 h, l;
    split2(v.x, h.x, l.x);
    split2(v.y, h.y, l.y);
    split2(v.z, h.z, l.z);
    split2(v.w, h.w, l.w);
    *reinterpret_cast<ushort4*>(hi + i) = h;
    *reinterpret_cast<ushort4*>(lo + i) = l;
}

// sum 4 partial fp32 buffers (stride n) -> (hi,lo) bf16
__global__ __launch_bounds__(256)
void reduce4_split(const float* __restrict__ p, u16* __restrict__ hi, u16* __restrict__ lo,
                   long n)
{
    const long i = ((long)blockIdx.x * 256 + threadIdx.x) * 4;
    const float4 a = *reinterpret_cast<const float4*>(p + i);
    const float4 b = *reinterpret_cast<const float4*>(p + n + i);
    const float4 c = *reinterpret_cast<const float4*>(p + 2 * n + i);
    const float4 d = *reinterpret_cast<const float4*>(p + 3 * n + i);
    ushort4 h, l;
    split2((a.x + b.x) + (c.x + d.x), h.x, l.x);
    split2((a.y + b.y) + (c.y + d.y), h.y, l.y);
    split2((a.z + b.z) + (c.z + d.z), h.z, l.z);
    split2((a.w + b.w) + (c.w + d.w), h.w, l.w);
    *reinterpret_cast<ushort4*>(hi + i) = h;
    *reinterpret_cast<ushort4*>(lo + i) = l;
}

// float (R x C) -> transposed (C x R) bf16 hi (+lo if HILO); batched via blockIdx.z
template<bool HILO>
__global__ __launch_bounds__(256)
void split_tr(const float* __restrict__ in, u16* __restrict__ hi, u16* __restrict__ lo,
              int R, int C, long sIn, long sOut)
{
    in += (long)blockIdx.z * sIn;
    hi += (long)blockIdx.z * sOut;
    if (HILO) lo += (long)blockIdx.z * sOut;

    __shared__ float tile[32][33];
    const int tx = threadIdx.x & 31, ty = threadIdx.x >> 5;   // 32 x 8
    const int r0 = blockIdx.y * 32, c0 = blockIdx.x * 32;

    #pragma unroll
    for (int j = 0; j < 4; j++)
        tile[ty * 4 + j][tx] = in[(long)(r0 + ty * 4 + j) * C + c0 + tx];
    __syncthreads();

    #pragma unroll
    for (int j = 0; j < 4; j++) {
        const int oc = ty * 4 + j;
        const float v = tile[tx][oc];
        u16 h, l; split2(v, h, l);
        const long o = (long)(c0 + oc) * R + r0 + tx;
        hi[o] = h;
        if (HILO) lo[o] = l;
    }
}

// row softmax over 2048 fp32 logits -> bf16 (hi only) probabilities
__global__ __launch_bounds__(256)
void softmax_hi(const float* __restrict__ S, u16* __restrict__ hi)
{
    const int NC = 2048;
    const long base = (long)blockIdx.x * NC;
    const float* p = S + base;
    const int tid = threadIdx.x;

    float4 v0 = reinterpret_cast<const float4*>(p)[tid];
    float4 v1 = reinterpret_cast<const float4*>(p)[tid + 256];

    float m = fmaxf(fmaxf(fmaxf(v0.x, v0.y), fmaxf(v0.z, v0.w)),
                    fmaxf(fmaxf(v1.x, v1.y), fmaxf(v1.z, v1.w)));
    #pragma unroll
    for (int off = 1; off < 64; off <<= 1)
        m = fmaxf(m, __shfl_xor(m, off));

    __shared__ float redm[4];
    __shared__ float reds[4];
    const int wave = tid >> 6, lane = tid & 63;
    if (lane == 0) redm[wave] = m;
    __syncthreads();
    m = fmaxf(fmaxf(redm[0], redm[1]), fmaxf(redm[2], redm[3]));

    v0.x = __expf(v0.x - m); v0.y = __expf(v0.y - m);
    v0.z = __expf(v0.z - m); v0.w = __expf(v0.w - m);
    v1.x = __expf(v1.x - m); v1.y = __expf(v1.y - m);
    v1.z = __expf(v1.z - m); v1.w = __expf(v1.w - m);

    float s = (v0.x + v0.y + v0.z + v0.w) + (v1.x + v1.y + v1.z + v1.w);
    #pragma unroll
    for (int off = 1; off < 64; off <<= 1)
        s += __shfl_xor(s, off);
    if (lane == 0) reds[wave] = s;
    __syncthreads();
    s = (reds[0] + reds[1]) + (reds[2] + reds[3]);

    const float inv = 1.0f / s;
    ushort4 h0, h1;
    h0.x = f2bf(v0.x * inv); h0.y = f2bf(v0.y * inv);
    h0.z = f2bf(v0.z * inv); h0.w = f2bf(v0.w * inv);
    h1.x = f2bf(v1.x * inv); h1.y = f2bf(v1.y * inv);
    h1.z = f2bf(v1.z * inv); h1.w = f2bf(v1.w * inv);

    reinterpret_cast<ushort4*>(hi + base)[tid]       = h0;
    reinterpret_cast<ushort4*>(hi + base)[tid + 256] = h1;
}

extern "C" void kernel_launch(void* const* d_in, const int* in_sizes, int n_in,
                              void* d_out, int out_size, void* d_ws, size_t ws_size,
                              hipStream_t stream)
{
    (void)in_sizes; (void)n_in; (void)out_size; (void)ws_size;
    const float* X = (const float*)d_in[0];   // (4,2048,1024)
    const float* R = (const float*)d_in[1];   // (1024,1024)
    const float* E = (const float*)d_in[2];   // (1024,1024)
    float* out = (float*)d_out;

    const int B = 4, SQ = 2048, D = 1024;
    const long NDX = (long)B * SQ * D;        // 8388608
    const long DD  = (long)D * D;             // 1048576
    const long SS  = (long)B * SQ * SQ;       // 16777216
    const long M16 = 8388608;                 // u16 elems per 16 MiB

    u16* wsu = (u16*)d_ws;
    // [0,32MB):  Xhi(16) Xlo(16)      -> after S-gemm: Xthi at [0,16)
    // [32,64MB): Rhi Rlo Ehi Elo (8)  -> Yhi(16) Ylo(16) -> Shi(32)
    // [64,128MB): Wpart(16) Wthi/Wtlo(4, at 80MB) -> Sf(64)
    u16* Xhi  = wsu;
    u16* Xlo  = Xhi + NDX;
    u16* Rhi  = wsu + 2 * M16;                // 32MB
    u16* Rlo  = Rhi + DD;
    u16* Ehi  = Rlo + DD;
    u16* Elo  = Ehi + DD;
    u16* Yhi  = wsu + 2 * M16;                // 32MB (R/E dead by then)
    u16* Ylo  = Yhi + NDX;
    u16* Shi  = wsu + 2 * M16;                // 32MB (Y dead by then)
    u16* Xthi = wsu;                          // (X splits dead by then)
    float* Wpart = (float*)(wsu + 4 * M16);   // 64MB: 4 x DD fp32 = 16MB
    u16* Wthi = wsu + 5 * M16;                // 80MB
    u16* Wtlo = Wthi + DD;
    float* Sf = (float*)(wsu + 4 * M16);      // 64MB..128MB (Wpart/Wt dead)

    dim3 thr(256);

    // split inputs (row-major; NT-form GEMMs below need no transposes)
    split_rm<<<dim3((unsigned)(NDX / 1024)), thr, 0, stream>>>(X, Xhi, Xlo);
    split_rm<<<dim3((unsigned)(DD / 1024)), thr, 0, stream>>>(R, Rhi, Rlo);
    split_rm<<<dim3((unsigned)(DD / 1024)), thr, 0, stream>>>(E, Ehi, Elo);

    // Wt = E @ R^T  (= (R E^T)^T), K-split x4 into fp32 partials
    gemm_split<EP_F32, true><<<dim3(D / 128, D / 128, 4), thr, 0, stream>>>(
        Ehi, Elo, Rhi, Rlo, Wpart, nullptr, nullptr,
        256, D, D, D, 256, 256, DD, 1.0f);
    reduce4_split<<<dim3((unsigned)(DD / 1024)), thr, 0, stream>>>(Wpart, Wthi, Wtlo, DD);

    // Y = X @ Wt^T = X R E^T  -> hi/lo (8192 x 1024)
    gemm_split<EP_HILO, true><<<dim3(D / 128, (B * SQ) / 128, 1), thr, 0, stream>>>(
        Xhi, Xlo, Wthi, Wtlo, nullptr, Yhi, Ylo,
        D, D, D, D, 0, 0, 0, 1.0f);

    // S = Y X^T / 32 (fp32 logits; B operand is X as stored) — 8-phase 256^2
    gemm_triple_8ph<<<dim3(SQ / 256, SQ / 256, B), dim3(512), 0, stream>>>(
        Yhi, Ylo, Xhi, Xlo, Sf,
        D, D, D, SQ,
        (long)SQ * D, (long)SQ * D, (long)SQ * SQ, 0.03125f);

    // softmax fp32 -> probability hi into Shi (Y dead)
    softmax_hi<<<dim3(B * SQ), thr, 0, stream>>>(Sf, Shi);

    // Xt (per batch 1024x2048) hi-only (X splits dead)
    split_tr<false><<<dim3(D / 32, SQ / 32, B), thr, 0, stream>>>(
        X, Xthi, nullptr, SQ, D, (long)SQ * D, (long)SQ * D);

    // O = sigmoid(S @ X), single-bf16 MFMA
    gemm_split<EP_SIG, false><<<dim3(D / 128, SQ / 128, B), thr, 0, stream>>>(
        Shi, nullptr, Xthi, nullptr, out, nullptr, nullptr,
        SQ, SQ, SQ, D,
        (long)SQ * SQ, (long)SQ * D, (long)SQ * D, 1.0f);
}

// Round 6
// 251.102 us; speedup vs baseline: 4.9141x; 1.0896x over previous
//
#include <hip/hip_runtime.h>
#include <hip/hip_bf16.h>
#include <math.h>

// SelfAttentionHybrid via split-bf16 (hi+lo) triple-MFMA fp32 emulation,
// using the algebraic rewrite  QK^T = X (R E^T) X^T:
//   Wt = E @ R^T           (1024^3, K-split x4 + reduce; Wt = (R E^T)^T)
//   Y  = X @ (Wt)^T = X R E^T        (8192x1024x1024, triple)
//   S  = softmax(Y X^T / 32)         (4 x 2048x2048, K=1024, triple, 256^2 tile)
//   O  = sigmoid(S @ X)              (4 x 2048x1024, K=2048, single bf16 MFMA)
// Triple GEMMs: acc += Ahi*Bhi + Ahi*Blo + Alo*Bhi  (lo*lo ~2^-18 dropped).
// All GEMM kernels: double-buffered LDS, ONE __syncthreads per K-tile
// (its implicit vmcnt(0)+lgkmcnt(0) covers both staging-done and read-drain),
// B-fragments register-held (read once), A-frags pipelined by the scheduler.

using u16 = unsigned short;
using short8 = __attribute__((ext_vector_type(8))) short;
using f32x4  = __attribute__((ext_vector_type(4))) float;

#define MFB(a, b, c) __builtin_amdgcn_mfma_f32_16x16x32_bf16((a), (b), (c), 0, 0, 0)

__device__ static inline u16 f2bf(float f) {
    union { __hip_bfloat16 h; u16 u; } cv; cv.h = __float2bfloat16(f); return cv.u;
}
__device__ static inline float bf2f(u16 u) {
    union { __hip_bfloat16 h; u16 u; } cv; cv.u = u; return __bfloat162float(cv.h);
}
__device__ static inline void split2(float v, u16& h, u16& l) {
    h = f2bf(v);
    l = f2bf(v - bf2f(h));
}

__device__ static inline void gload16(const u16* g, u16* l) {
    __builtin_amdgcn_global_load_lds(
        (const __attribute__((address_space(1))) void*)g,
        (__attribute__((address_space(3))) void*)l, 16, 0, 0);
}

// LDS tile layout: [rows][32 bf16], row = 64B. 16B chunk index is
// XOR-swizzled: chunk slot c holds k-group g = c ^ ((row>>1)&3).
// Readers (16 consecutive rows at fixed k-group) spread 2-way max (free).
__device__ static inline short8 ldfrag(const u16* sm, int row, int g) {
    const int off = row * 32 + ((g ^ ((row >> 1) & 3)) << 3);
    return *reinterpret_cast<const short8*>(sm + off);
}

enum { EP_F32 = 0, EP_HILO = 1, EP_SIG = 2 };

// ---------------------------------------------------------------------------
// 128^2 tile kernel (W, Y, PV). 256 thr / 4 waves (2x2), wave tile 64x64.
// Double-buffered: LDS = 2 x NTILE x 8KB.
// ---------------------------------------------------------------------------
template<int EPI, bool TRIPLE>
__global__ __launch_bounds__(256)
void gemm_split(const u16* __restrict__ Ahi, const u16* __restrict__ Alo,
                const u16* __restrict__ Bhi, const u16* __restrict__ Blo,
                float* __restrict__ Cf, u16* __restrict__ Chi, u16* __restrict__ Clo,
                int K, int lda, int ldb, int ldc,
                long sA, long sB, long sC, float alpha)
{
    const int z = blockIdx.z;
    Ahi += z * sA;
    Bhi += z * sB;
    if (TRIPLE) { Alo += z * sA; Blo += z * sB; }
    if (EPI == EP_HILO) { Chi += z * sC; Clo += z * sC; }
    else                { Cf  += z * sC; }

    constexpr int BUFSZ  = TRIPLE ? 16384 : 8192;    // u16 per buffer
    constexpr int OFF_BH = TRIPLE ? 8192 : 4096;
    __shared__ __align__(16) u16 smem[2 * BUFSZ];

    const int t = threadIdx.x;
    const int wave = t >> 6, lane = t & 63;
    const int row0 = blockIdx.y * 128, col0 = blockIdx.x * 128;

    const int rr = t >> 2, cc = t & 3;
    const int gg = cc ^ ((rr >> 1) & 3);
    const u16* gAh = Ahi + (long)(row0 + rr) * lda + gg * 8;
    const u16* gBh = Bhi + (long)(col0 + rr) * ldb + gg * 8;
    const u16* gAl = TRIPLE ? (Alo + (long)(row0 + rr) * lda + gg * 8) : nullptr;
    const u16* gBl = TRIPLE ? (Blo + (long)(col0 + rr) * ldb + gg * 8) : nullptr;
    const long a2 = (long)64 * lda, b2 = (long)64 * ldb;

    f32x4 acc[4][4];
    #pragma unroll
    for (int m = 0; m < 4; m++)
        #pragma unroll
        for (int n = 0; n < 4; n++)
            acc[m][n] = (f32x4){0.f, 0.f, 0.f, 0.f};

    const int lr = lane & 15, lg = lane >> 4;
    const int wm = (wave >> 1) * 64, wn = (wave & 1) * 64;
    const int NT = K >> 5;

    // prologue: stage K-tile 0 into buf 0
    {
        u16* d = smem + t * 8;
        gload16(gAh,      d);
        gload16(gAh + a2, d + 2048);
        gload16(gBh,      d + OFF_BH);
        gload16(gBh + b2, d + OFF_BH + 2048);
        if (TRIPLE) {
            gload16(gAl,      d + 4096);
            gload16(gAl + a2, d + 4096 + 2048);
            gload16(gBl,      d + 12288);
            gload16(gBl + b2, d + 12288 + 2048);
        }
    }

    for (int tk = 0; tk < NT; ++tk) {
        __syncthreads();    // implicit vmcnt(0)+lgkmcnt(0): staging landed, reads drained
        const u16* sb = smem + (tk & 1) * BUFSZ;
        if (tk + 1 < NT) {
            const int kn = (tk + 1) << 5;
            u16* d = smem + ((tk + 1) & 1) * BUFSZ + t * 8;
            gload16(gAh + kn,      d);
            gload16(gAh + kn + a2, d + 2048);
            gload16(gBh + kn,      d + OFF_BH);
            gload16(gBh + kn + b2, d + OFF_BH + 2048);
            if (TRIPLE) {
                gload16(gAl + kn,      d + 4096);
                gload16(gAl + kn + a2, d + 4096 + 2048);
                gload16(gBl + kn,      d + 12288);
                gload16(gBl + kn + b2, d + 12288 + 2048);
            }
        }
        const u16* sAh = sb;
        const u16* sAl = sb + 4096;
        const u16* sBh = sb + OFF_BH;
        const u16* sBl = sb + 12288;

        short8 bh[4], bl[4];
        #pragma unroll
        for (int n = 0; n < 4; n++) {
            bh[n] = ldfrag(sBh, wn + n * 16 + lr, lg);
            if (TRIPLE) bl[n] = ldfrag(sBl, wn + n * 16 + lr, lg);
        }
        #pragma unroll
        for (int m = 0; m < 4; m++) {
            const short8 ah = ldfrag(sAh, wm + m * 16 + lr, lg);
            short8 al;
            if (TRIPLE) al = ldfrag(sAl, wm + m * 16 + lr, lg);
            #pragma unroll
            for (int n = 0; n < 4; n++) {
                acc[m][n] = MFB(ah, bh[n], acc[m][n]);
                if (TRIPLE) {
                    acc[m][n] = MFB(ah, bl[n], acc[m][n]);
                    acc[m][n] = MFB(al, bh[n], acc[m][n]);
                }
            }
        }
    }

    // ---- epilogue: C/D layout col=lane&15, row=(lane>>4)*4+reg ----
    #pragma unroll
    for (int m = 0; m < 4; m++) {
        #pragma unroll
        for (int n = 0; n < 4; n++) {
            #pragma unroll
            for (int r = 0; r < 4; r++) {
                const int grow = row0 + wm + m * 16 + lg * 4 + r;
                const int gcol = col0 + wn + n * 16 + lr;
                const float v = alpha * acc[m][n][r];
                const long o = (long)grow * ldc + gcol;
                if (EPI == EP_F32) {
                    Cf[o] = v;
                } else if (EPI == EP_SIG) {
                    Cf[o] = 1.0f / (1.0f + __expf(-v));
                } else {
                    u16 h, l; split2(v, h, l);
                    Chi[o] = h; Clo[o] = l;
                }
            }
        }
    }
}

// ---------------------------------------------------------------------------
// 256^2 triple kernel (S-gemm). 512 thr / 8 waves (2M x 4N), wave tile 128x64.
// LDS 128 KiB: [2 buf][Ah(16K)|Al|Bh|Bl]. One __syncthreads per K-tile.
// B-frags (8 pairs) register-held; A-frags pipelined through the m-loop.
// ---------------------------------------------------------------------------
__global__ __launch_bounds__(512)
void gemm_triple_256(const u16* __restrict__ Ahi, const u16* __restrict__ Alo,
                     const u16* __restrict__ Bhi, const u16* __restrict__ Blo,
                     float* __restrict__ Cf,
                     int K, int lda, int ldb, int ldc,
                     long sA, long sB, long sC, float alpha)
{
    const int z = blockIdx.z;
    Ahi += z * sA; Alo += z * sA;
    Bhi += z * sB; Blo += z * sB;
    Cf  += z * sC;

    __shared__ __align__(16) u16 smem[65536];   // 128 KiB

    const int t = threadIdx.x;
    const int wave = t >> 6, lane = t & 63;
    const int lr = lane & 15, lg = lane >> 4;
    const int row0 = blockIdx.y * 256, col0 = blockIdx.x * 256;
    const int wm = (wave >> 2) * 128, wn = (wave & 3) * 64;

    const int srow = t >> 2;
    const int sg = (t & 3) ^ ((srow >> 1) & 3);
    const u16* gAh = Ahi + (long)(row0 + srow) * lda + sg * 8;
    const u16* gAl = Alo + (long)(row0 + srow) * lda + sg * 8;
    const u16* gBh = Bhi + (long)(col0 + srow) * ldb + sg * 8;
    const u16* gBl = Blo + (long)(col0 + srow) * ldb + sg * 8;
    const long a2 = (long)128 * lda, b2 = (long)128 * ldb;

    f32x4 acc[8][4];
    #pragma unroll
    for (int m = 0; m < 8; m++)
        #pragma unroll
        for (int n = 0; n < 4; n++)
            acc[m][n] = (f32x4){0.f, 0.f, 0.f, 0.f};

    const int NT = K >> 5;

    // prologue: stage K-tile 0 into buf 0
    {
        u16* d = smem + t * 8;
        gload16(gAh,      d);          gload16(gAh + a2, d + 4096);
        gload16(gAl,      d + 8192);   gload16(gAl + a2, d + 12288);
        gload16(gBh,      d + 16384);  gload16(gBh + b2, d + 20480);
        gload16(gBl,      d + 24576);  gload16(gBl + b2, d + 28672);
    }

    for (int tk = 0; tk < NT; ++tk) {
        __syncthreads();    // implicit vmcnt(0)+lgkmcnt(0)
        const u16* sb = smem + (tk & 1) * 32768;
        if (tk + 1 < NT) {
            const int kn = (tk + 1) << 5;
            u16* d = smem + ((tk + 1) & 1) * 32768 + t * 8;
            gload16(gAh + kn,      d);          gload16(gAh + kn + a2, d + 4096);
            gload16(gAl + kn,      d + 8192);   gload16(gAl + kn + a2, d + 12288);
            gload16(gBh + kn,      d + 16384);  gload16(gBh + kn + b2, d + 20480);
            gload16(gBl + kn,      d + 24576);  gload16(gBl + kn + b2, d + 28672);
        }
        const u16* sAh = sb;
        const u16* sAl = sb + 8192;
        const u16* sBh = sb + 16384;
        const u16* sBl = sb + 24576;

        short8 bh[4], bl[4];
        #pragma unroll
        for (int n = 0; n < 4; n++) {
            bh[n] = ldfrag(sBh, wn + n * 16 + lr, lg);
            bl[n] = ldfrag(sBl, wn + n * 16 + lr, lg);
        }
        #pragma unroll
        for (int m = 0; m < 8; m++) {
            const short8 ah = ldfrag(sAh, wm + m * 16 + lr, lg);
            const short8 al = ldfrag(sAl, wm + m * 16 + lr, lg);
            #pragma unroll
            for (int n = 0; n < 4; n++) {
                acc[m][n] = MFB(ah, bh[n], acc[m][n]);
                acc[m][n] = MFB(ah, bl[n], acc[m][n]);
                acc[m][n] = MFB(al, bh[n], acc[m][n]);
            }
        }
    }

    // ---- epilogue ----
    #pragma unroll
    for (int m = 0; m < 8; m++) {
        #pragma unroll
        for (int n = 0; n < 4; n++) {
            #pragma unroll
            for (int r = 0; r < 4; r++) {
                const int grow = row0 + wm + m * 16 + lg * 4 + r;
                const int gcol = col0 + wn + n * 16 + lr;
                Cf[(long)grow * ldc + gcol] = alpha * acc[m][n][r];
            }
        }
    }
}

// float -> (hi,lo) bf16, row-major, 4 elems/thread
__global__ __launch_bounds__(256)
void split_rm(const float* __restrict__ in, u16* __restrict__ hi, u16* __restrict__ lo)
{
    const long i = ((long)blockIdx.x * 256 + threadIdx.x) * 4;
    const float4 v = *reinterpret_cast<const float4*>(in + i);
    ushort4 h, l;
    split2(v.x, h.x, l.x);
    split2(v.y, h.y, l.y);
    split2(v.z, h.z, l.z);
    split2(v.w, h.w, l.w);
    *reinterpret_cast<ushort4*>(hi + i) = h;
    *reinterpret_cast<ushort4*>(lo + i) = l;
}

// sum 4 partial fp32 buffers (stride n) -> (hi,lo) bf16
__global__ __launch_bounds__(256)
void reduce4_split(const float* __restrict__ p, u16* __restrict__ hi, u16* __restrict__ lo,
                   long n)
{
    const long i = ((long)blockIdx.x * 256 + threadIdx.x) * 4;
    const float4 a = *reinterpret_cast<const float4*>(p + i);
    const float4 b = *reinterpret_cast<const float4*>(p + n + i);
    const float4 c = *reinterpret_cast<const float4*>(p + 2 * n + i);
    const float4 d = *reinterpret_cast<const float4*>(p + 3 * n + i);
    ushort4 h, l;
    split2((a.x + b.x) + (c.x + d.x), h.x, l.x);
    split2((a.y + b.y) + (c.y + d.y), h.y, l.y);
    split2((a.z + b.z) + (c.z + d.z), h.z, l.z);
    split2((a.w + b.w) + (c.w + d.w), h.w, l.w);
    *reinterpret_cast<ushort4*>(hi + i) = h;
    *reinterpret_cast<ushort4*>(lo + i) = l;
}

// float (R x C) -> transposed (C x R) bf16 hi (+lo if HILO); batched via blockIdx.z
template<bool HILO>
__global__ __launch_bounds__(256)
void split_tr(const float* __restrict__ in, u16* __restrict__ hi, u16* __restrict__ lo,
              int R, int C, long sIn, long sOut)
{
    in += (long)blockIdx.z * sIn;
    hi += (long)blockIdx.z * sOut;
    if (HILO) lo += (long)blockIdx.z * sOut;

    __shared__ float tile[32][33];
    const int tx = threadIdx.x & 31, ty = threadIdx.x >> 5;   // 32 x 8
    const int r0 = blockIdx.y * 32, c0 = blockIdx.x * 32;

    #pragma unroll
    for (int j = 0; j < 4; j++)
        tile[ty * 4 + j][tx] = in[(long)(r0 + ty * 4 + j) * C + c0 + tx];
    __syncthreads();

    #pragma unroll
    for (int j = 0; j < 4; j++) {
        const int oc = ty * 4 + j;
        const float v = tile[tx][oc];
        u16 h, l; split2(v, h, l);
        const long o = (long)(c0 + oc) * R + r0 + tx;
        hi[o] = h;
        if (HILO) lo[o] = l;
    }
}

// row softmax over 2048 fp32 logits -> bf16 (hi only) probabilities
__global__ __launch_bounds__(256)
void softmax_hi(const float* __restrict__ S, u16* __restrict__ hi)
{
    const int NC = 2048;
    const long base = (long)blockIdx.x * NC;
    const float* p = S + base;
    const int tid = threadIdx.x;

    float4 v0 = reinterpret_cast<const float4*>(p)[tid];
    float4 v1 = reinterpret_cast<const float4*>(p)[tid + 256];

    float m = fmaxf(fmaxf(fmaxf(v0.x, v0.y), fmaxf(v0.z, v0.w)),
                    fmaxf(fmaxf(v1.x, v1.y), fmaxf(v1.z, v1.w)));
    #pragma unroll
    for (int off = 1; off < 64; off <<= 1)
        m = fmaxf(m, __shfl_xor(m, off));

    __shared__ float redm[4];
    __shared__ float reds[4];
    const int wave = tid >> 6, lane = tid & 63;
    if (lane == 0) redm[wave] = m;
    __syncthreads();
    m = fmaxf(fmaxf(redm[0], redm[1]), fmaxf(redm[2], redm[3]));

    v0.x = __expf(v0.x - m); v0.y = __expf(v0.y - m);
    v0.z = __expf(v0.z - m); v0.w = __expf(v0.w - m);
    v1.x = __expf(v1.x - m); v1.y = __expf(v1.y - m);
    v1.z = __expf(v1.z - m); v1.w = __expf(v1.w - m);

    float s = (v0.x + v0.y + v0.z + v0.w) + (v1.x + v1.y + v1.z + v1.w);
    #pragma unroll
    for (int off = 1; off < 64; off <<= 1)
        s += __shfl_xor(s, off);
    if (lane == 0) reds[wave] = s;
    __syncthreads();
    s = (reds[0] + reds[1]) + (reds[2] + reds[3]);

    const float inv = 1.0f / s;
    ushort4 h0, h1;
    h0.x = f2bf(v0.x * inv); h0.y = f2bf(v0.y * inv);
    h0.z = f2bf(v0.z * inv); h0.w = f2bf(v0.w * inv);
    h1.x = f2bf(v1.x * inv); h1.y = f2bf(v1.y * inv);
    h1.z = f2bf(v1.z * inv); h1.w = f2bf(v1.w * inv);

    reinterpret_cast<ushort4*>(hi + base)[tid]       = h0;
    reinterpret_cast<ushort4*>(hi + base)[tid + 256] = h1;
}

extern "C" void kernel_launch(void* const* d_in, const int* in_sizes, int n_in,
                              void* d_out, int out_size, void* d_ws, size_t ws_size,
                              hipStream_t stream)
{
    (void)in_sizes; (void)n_in; (void)out_size; (void)ws_size;
    const float* X = (const float*)d_in[0];   // (4,2048,1024)
    const float* R = (const float*)d_in[1];   // (1024,1024)
    const float* E = (const float*)d_in[2];   // (1024,1024)
    float* out = (float*)d_out;

    const int B = 4, SQ = 2048, D = 1024;
    const long NDX = (long)B * SQ * D;        // 8388608
    const long DD  = (long)D * D;             // 1048576
    const long SS  = (long)B * SQ * SQ;       // 16777216
    const long M16 = 8388608;                 // u16 elems per 16 MiB

    u16* wsu = (u16*)d_ws;
    // [0,32MB):  Xhi(16) Xlo(16)      -> after S-gemm: Xthi at [0,16)
    // [32,64MB): Rhi Rlo Ehi Elo (8)  -> Yhi(16) Ylo(16) -> Shi(32)
    // [64,128MB): Wpart(16) Wthi/Wtlo(4, at 80MB) -> Sf(64)
    u16* Xhi  = wsu;
    u16* Xlo  = Xhi + NDX;
    u16* Rhi  = wsu + 2 * M16;                // 32MB
    u16* Rlo  = Rhi + DD;
    u16* Ehi  = Rlo + DD;
    u16* Elo  = Ehi + DD;
    u16* Yhi  = wsu + 2 * M16;                // 32MB (R/E dead by then)
    u16* Ylo  = Yhi + NDX;
    u16* Shi  = wsu + 2 * M16;                // 32MB (Y dead by then)
    u16* Xthi = wsu;                          // (X splits dead by then)
    float* Wpart = (float*)(wsu + 4 * M16);   // 64MB: 4 x DD fp32 = 16MB
    u16* Wthi = wsu + 5 * M16;                // 80MB
    u16* Wtlo = Wthi + DD;
    float* Sf = (float*)(wsu + 4 * M16);      // 64MB..128MB (Wpart/Wt dead)

    dim3 thr(256);

    // split inputs (row-major; NT-form GEMMs below need no transposes)
    split_rm<<<dim3((unsigned)(NDX / 1024)), thr, 0, stream>>>(X, Xhi, Xlo);
    split_rm<<<dim3((unsigned)(DD / 1024)), thr, 0, stream>>>(R, Rhi, Rlo);
    split_rm<<<dim3((unsigned)(DD / 1024)), thr, 0, stream>>>(E, Ehi, Elo);

    // Wt = E @ R^T  (= (R E^T)^T), K-split x4 into fp32 partials
    gemm_split<EP_F32, true><<<dim3(D / 128, D / 128, 4), thr, 0, stream>>>(
        Ehi, Elo, Rhi, Rlo, Wpart, nullptr, nullptr,
        256, D, D, D, 256, 256, DD, 1.0f);
    reduce4_split<<<dim3((unsigned)(DD / 1024)), thr, 0, stream>>>(Wpart, Wthi, Wtlo, DD);

    // Y = X @ Wt^T = X R E^T  -> hi/lo (8192 x 1024)
    gemm_split<EP_HILO, true><<<dim3(D / 128, (B * SQ) / 128, 1), thr, 0, stream>>>(
        Xhi, Xlo, Wthi, Wtlo, nullptr, Yhi, Ylo,
        D, D, D, D, 0, 0, 0, 1.0f);

    // S = Y X^T / 32 (fp32 logits; B operand is X as stored) — 256^2 pipelined
    gemm_triple_256<<<dim3(SQ / 256, SQ / 256, B), dim3(512), 0, stream>>>(
        Yhi, Ylo, Xhi, Xlo, Sf,
        D, D, D, SQ,
        (long)SQ * D, (long)SQ * D, (long)SQ * SQ, 0.03125f);

    // softmax fp32 -> probability hi into Shi (Y dead)
    softmax_hi<<<dim3(B * SQ), thr, 0, stream>>>(Sf, Shi);

    // Xt (per batch 1024x2048) hi-only (X splits dead)
    split_tr<false><<<dim3(D / 32, SQ / 32, B), thr, 0, stream>>>(
        X, Xthi, nullptr, SQ, D, (long)SQ * D, (long)SQ * D);

    // O = sigmoid(S @ X), single-bf16 MFMA
    gemm_split<EP_SIG, false><<<dim3(D / 128, SQ / 128, B), thr, 0, stream>>>(
        Shi, nullptr, Xthi, nullptr, out, nullptr, nullptr,
        SQ, SQ, SQ, D,
        (long)SQ * SQ, (long)SQ * D, (long)SQ * D, 1.0f);
}